// Round 4
// baseline (405.960 us; speedup 1.0000x reference)
//
#include <hip/hip_runtime.h>
#include <stdint.h>

#define DEV __device__ __forceinline__

typedef float f32x4 __attribute__((ext_vector_type(4)));
typedef float f32x16 __attribute__((ext_vector_type(16)));
typedef __bf16 bf16x8 __attribute__((ext_vector_type(8)));
typedef __bf16 bf16x4 __attribute__((ext_vector_type(4)));
typedef unsigned short u16x4 __attribute__((ext_vector_type(4)));
typedef unsigned short u16x8 __attribute__((ext_vector_type(8)));
typedef unsigned u32x4 __attribute__((ext_vector_type(4)));

// ---------- helpers ----------
DEV unsigned short f2bf(float f) {
  unsigned u = __builtin_bit_cast(unsigned, f);
  u += 0x7fffu + ((u >> 16) & 1u);   // RNE
  return (unsigned short)(u >> 16);
}
DEV float bf2f(unsigned short h) {
  unsigned u = ((unsigned)h) << 16;
  return __builtin_bit_cast(float, u);
}
DEV unsigned pkbf(float lo, float hi) {  // D.lo=bf16(S0), D.hi=bf16(S1)
  unsigned r;
  asm("v_cvt_pk_bf16_f32 %0, %1, %2" : "=v"(r) : "v"(lo), "v"(hi));
  return r;
}
DEV void gload_lds16(const void* g, void* l) {
  __builtin_amdgcn_global_load_lds((const __attribute__((address_space(1))) void*)g,
                                   (__attribute__((address_space(3))) void*)l, 16, 0, 0);
}

// ---------- elementwise f32 -> bf16 ----------
__global__ void cvt_f32_bf16(const float* __restrict__ in, unsigned short* __restrict__ out, int n) {
  int i = (blockIdx.x * 256 + threadIdx.x) * 4;
  if (i >= n) return;
  f32x4 v = *(const f32x4*)(in + i);
  u16x4 o;
  o[0] = f2bf(v[0]); o[1] = f2bf(v[1]); o[2] = f2bf(v[2]); o[3] = f2bf(v[3]);
  *(u16x4*)(out + i) = o;
}

// ---------- generic f32 [R][C] -> bf16 [C][R] transpose (64x64 tiles) ----------
__global__ void transpose_cvt(const float* __restrict__ src, unsigned short* __restrict__ dst,
                              int R, int C) {
  __shared__ __align__(16) float t[64][65];
  const int tid = threadIdx.x;
  const int r0 = blockIdx.x * 64, c0 = blockIdx.y * 64;
  const int rr = tid >> 2, q = tid & 3;
  const float* s = src + (size_t)(r0 + rr) * C + c0 + q * 16;
#pragma unroll
  for (int j = 0; j < 4; ++j) {
    f32x4 v = *(const f32x4*)(s + j * 4);
    t[rr][q * 16 + j * 4 + 0] = v[0];
    t[rr][q * 16 + j * 4 + 1] = v[1];
    t[rr][q * 16 + j * 4 + 2] = v[2];
    t[rr][q * 16 + j * 4 + 3] = v[3];
  }
  __syncthreads();
  const int cc = tid >> 2, qq = tid & 3;
  unsigned short* o = dst + (size_t)(c0 + cc) * R + r0 + qq * 16;
  u16x8 a, b;
#pragma unroll
  for (int j = 0; j < 8; ++j) {
    a[j] = f2bf(t[qq * 16 + j][cc]);
    b[j] = f2bf(t[qq * 16 + 8 + j][cc]);
  }
  *(u16x8*)o = a;
  *(u16x8*)(o + 8) = b;
}

// ---------- pack per-head Wq/Wk/Wv [16][1024][64] -> Bt bf16 [3072][1024] ----------
__global__ void pack_qkv_w(const float* __restrict__ Wq, const float* __restrict__ Wk,
                           const float* __restrict__ Wv, unsigned short* __restrict__ dst) {
  __shared__ __align__(16) float t[64][65];
  const int tid = threadIdx.x;
  const int z = blockIdx.z, part = z >> 4, h = z & 15;
  const float* src = (part == 0 ? Wq : (part == 1 ? Wk : Wv)) + (size_t)h * 65536;
  const int r0 = blockIdx.x * 64;  // d tile
  const int rr = tid >> 2, q = tid & 3;
  const float* s = src + (size_t)(r0 + rr) * 64 + q * 16;
#pragma unroll
  for (int j = 0; j < 4; ++j) {
    f32x4 v = *(const f32x4*)(s + j * 4);
    t[rr][q * 16 + j * 4 + 0] = v[0];
    t[rr][q * 16 + j * 4 + 1] = v[1];
    t[rr][q * 16 + j * 4 + 2] = v[2];
    t[rr][q * 16 + j * 4 + 3] = v[3];
  }
  __syncthreads();
  const int cc = tid >> 2, qq = tid & 3;  // cc = e
  unsigned short* o = dst + ((size_t)(part * 1024 + h * 64 + cc)) * 1024 + r0 + qq * 16;
  u16x8 a, b;
#pragma unroll
  for (int j = 0; j < 8; ++j) {
    a[j] = f2bf(t[qq * 16 + j][cc]);
    b[j] = f2bf(t[qq * 16 + 8 + j][cc]);
  }
  *(u16x8*)o = a;
  *(u16x8*)(o + 8) = b;
}

__global__ void pack_bias(const float* __restrict__ bq, const float* __restrict__ bk,
                          const float* __restrict__ bv, float* __restrict__ o) {
  int i = blockIdx.x * 256 + threadIdx.x;  // 0..3071
  o[i] = i < 1024 ? bq[i] : (i < 2048 ? bk[i - 1024] : bv[i - 2048]);
}

// ---------- transpose V [bh][2048][64] -> Vt [bh][64][2048] (bf16) ----------
__global__ void vtrans(const unsigned short* __restrict__ v, unsigned short* __restrict__ vt) {
  __shared__ __align__(16) unsigned short t[64][72];
  const int tid = threadIdx.x;
  const int bh = blockIdx.y, s0 = blockIdx.x * 64;
  const int r = tid >> 2, q = (tid & 3) * 16;
  const unsigned short* g = v + ((size_t)bh * 2048 + s0 + r) * 64 + q;
  *(u16x8*)&t[r][q] = *(const u16x8*)g;
  *(u16x8*)&t[r][q + 8] = *(const u16x8*)(g + 8);
  __syncthreads();
  const int d = tid >> 2, qq = (tid & 3) * 16;
  unsigned short* o = vt + ((size_t)bh * 64 + d) * 2048 + s0 + qq;
  u16x8 a, b;
#pragma unroll
  for (int j = 0; j < 8; ++j) {
    a[j] = t[qq + j][d];
    b[j] = t[qq + 8 + j][d];
  }
  *(u16x8*)o = a;
  *(u16x8*)(o + 8) = b;
}

// ================= 256x256 8-phase GEMM (T2+T3+T4+T5) =================
// out[M][N] = A[M][K] * Bt[N][K]^T + bias.  512 thr = 8 waves (2M x 4N),
// per-wave 128x64 C. LDS: 2 dbuf x (A[256][64] + B[256][64]) bf16 = 128 KB,
// XOR-swizzled (col_byte ^ (row&7)<<4), staged via pre-swizzled global src.
// K-tile units (16KB, 2 gload_lds/thread): U0=A{0-63,128-191} (read ph1-2),
// U1=A{64-127,192-255} (ph3-4), U2=B n-frags 0-1 rows (ph1), U3=B n-frags 2-3
// rows (ph2). Issue order per tile: U0,U2,U3,U1. Steady state: vmcnt(6) at
// phases 4/8 retires exactly through the next tile's last unit (3 units stay
// in flight). Tail iterations drain with vmcnt(0).
// MODE 1: relu->out; MODE 2: split q/k/v (+q pre-scale).
template <int MODE>
__global__ __launch_bounds__(512, 2) void gemm8(
    const unsigned short* __restrict__ A, const unsigned short* __restrict__ Bt,
    const float* __restrict__ bias, unsigned short* __restrict__ out,
    unsigned short* __restrict__ qb, unsigned short* __restrict__ kb,
    unsigned short* __restrict__ vb, int M, int N, int K, int NBN) {
  __shared__ __align__(16) char As[2][32768];
  __shared__ __align__(16) char Bs[2][32768];
  const int tid = threadIdx.x, wave = tid >> 6, lane = tid & 63;
  const int lrow = lane & 15, lgk = (lane >> 4) * 16;
  const int cr = lane >> 3;
  const int csw = ((lane & 7) * 16) ^ (cr << 4);
  const int nwg = gridDim.x, bid = blockIdx.x;
  const int wg = (bid & 7) * (nwg >> 3) + (bid >> 3);   // bijective (nwg%8==0)
  const int bm = wg / NBN, bn = wg % NBN;
  const int m0 = bm * 256, n0 = bn * 256;
  const int wm = (wave >> 2) * 128, wn = (wave & 3) * 64;
  const char* Ab = (const char*)A;
  const char* Bb = (const char*)Bt;
  const int NT = K >> 6;

  f32x4 acc[8][4] = {};
  bf16x8 af[4][2];                 // A quadrant frags (rewritten ph1 / ph3)
  bf16x8 bf0[2][2], bf1[2][2];     // B frags n0-1, n2-3 (live whole tile)

#define ISSUE_A(kt, half) do {                                                \
    _Pragma("unroll") for (int rep = 0; rep < 2; ++rep) {                     \
      const int j = wave * 2 + rep;                                           \
      const int row0 = j * 8 + ((j >= 8) ? 64 : 0) + (half) * 64;             \
      gload_lds16(Ab + (((size_t)(m0 + row0 + cr) * K + (kt) * 64) << 1) + csw,\
                  &As[(kt) & 1][row0 * 128]);                                 \
    } } while (0)
#define ISSUE_B(kt, half) do {                                                \
    _Pragma("unroll") for (int rep = 0; rep < 2; ++rep) {                     \
      const int j = wave * 2 + rep;                                           \
      const int row0 = (j >> 2) * 64 + (j & 3) * 8 + (half) * 32;             \
      gload_lds16(Bb + (((size_t)(n0 + row0 + cr) * K + (kt) * 64) << 1) + csw,\
                  &Bs[(kt) & 1][row0 * 128]);                                 \
    } } while (0)
#define READ_A(dbuf, mh) do {                                                 \
    _Pragma("unroll") for (int i = 0; i < 4; ++i) {                           \
      const int row = wm + ((mh) * 4 + i) * 16 + lrow;                        \
      const int sw = (row & 7) << 4;                                          \
      af[i][0] = *(const bf16x8*)&As[dbuf][row * 128 + (lgk ^ sw)];           \
      af[i][1] = *(const bf16x8*)&As[dbuf][row * 128 + ((64 + lgk) ^ sw)];    \
    } } while (0)
#define READ_B(dbuf, nh, bfx) do {                                            \
    _Pragma("unroll") for (int i = 0; i < 2; ++i) {                           \
      const int row = wn + ((nh) * 2 + i) * 16 + lrow;                        \
      const int sw = (row & 7) << 4;                                          \
      bfx[i][0] = *(const bf16x8*)&Bs[dbuf][row * 128 + (lgk ^ sw)];          \
      bfx[i][1] = *(const bf16x8*)&Bs[dbuf][row * 128 + ((64 + lgk) ^ sw)];   \
    } } while (0)
#define MFMA_Q(mh, nh, bfx) do {                                              \
    __builtin_amdgcn_s_setprio(1);                                            \
    _Pragma("unroll") for (int i = 0; i < 4; ++i)                             \
    _Pragma("unroll") for (int n = 0; n < 2; ++n)                             \
    _Pragma("unroll") for (int kk = 0; kk < 2; ++kk)                          \
      acc[(mh) * 4 + i][(nh) * 2 + n] = __builtin_amdgcn_mfma_f32_16x16x32_bf16(\
          af[i][kk], bfx[n][kk], acc[(mh) * 4 + i][(nh) * 2 + n], 0, 0, 0);   \
    __builtin_amdgcn_s_setprio(0);                                            \
  } while (0)
#define BAR() __builtin_amdgcn_s_barrier()
#define LGKM0() do { asm volatile("s_waitcnt lgkmcnt(0)" ::: "memory");       \
    __builtin_amdgcn_sched_barrier(0); } while (0)
#define VMCNT6() asm volatile("s_waitcnt vmcnt(6)" ::: "memory")
#define VMCNT0() asm volatile("s_waitcnt vmcnt(0)" ::: "memory")

  // prologue: tile 0 fully, drain, then tile 1 U0,U2,U3 (U1(1) at ph1)
  ISSUE_A(0, 0); ISSUE_B(0, 0); ISSUE_B(0, 1); ISSUE_A(0, 1);
  __syncthreads();
  ISSUE_A(1, 0); ISSUE_B(1, 0); ISSUE_B(1, 1);

  for (int a = 0; a < NT; a += 2) {
    const int d0 = a & 1, d1 = d0 ^ 1;
    const bool g2 = (a + 2) < NT, g3 = (a + 3) < NT;
    // ---- tile a ----
    // ph1
    READ_A(d0, 0); READ_B(d0, 0, bf0);
    ISSUE_A(a + 1, 1);                    // U1(a+1)
    BAR(); LGKM0();
    MFMA_Q(0, 0, bf0);
    BAR();
    // ph2
    READ_B(d0, 1, bf1);
    if (g2) ISSUE_A(a + 2, 0);            // U0(a+2)
    BAR(); LGKM0();
    MFMA_Q(0, 1, bf1);
    BAR();
    // ph3
    READ_A(d0, 1);
    if (g2) ISSUE_B(a + 2, 0);            // U2(a+2)
    BAR(); LGKM0();
    MFMA_Q(1, 0, bf0);
    BAR();
    // ph4
    if (g2) { ISSUE_B(a + 2, 1); VMCNT6(); } else { VMCNT0(); }
    BAR();
    MFMA_Q(1, 1, bf1);
    BAR();
    // ---- tile a+1 ----
    // ph5
    READ_A(d1, 0); READ_B(d1, 0, bf0);
    if (g2) ISSUE_A(a + 2, 1);            // U1(a+2)
    BAR(); LGKM0();
    MFMA_Q(0, 0, bf0);
    BAR();
    // ph6
    READ_B(d1, 1, bf1);
    if (g3) ISSUE_A(a + 3, 0);            // U0(a+3)
    BAR(); LGKM0();
    MFMA_Q(0, 1, bf1);
    BAR();
    // ph7
    READ_A(d1, 1);
    if (g3) ISSUE_B(a + 3, 0);            // U2(a+3)
    BAR(); LGKM0();
    MFMA_Q(1, 0, bf0);
    BAR();
    // ph8
    if (g3) { ISSUE_B(a + 3, 1); VMCNT6(); } else { VMCNT0(); }
    BAR();
    MFMA_Q(1, 1, bf1);
    BAR();
  }
#undef ISSUE_A
#undef ISSUE_B
#undef READ_A
#undef READ_B
#undef MFMA_Q
#undef BAR
#undef LGKM0
#undef VMCNT6
#undef VMCNT0

#pragma unroll
  for (int mi = 0; mi < 8; ++mi) {
    const int row = m0 + wm + mi * 16 + ((lane >> 4) << 2);
#pragma unroll
    for (int ni = 0; ni < 4; ++ni) {
      const int col = n0 + wn + ni * 16 + lrow;
      const float bvv = bias[col];
#pragma unroll
      for (int r = 0; r < 4; ++r) {
        float v = acc[mi][ni][r] + bvv;
        if (MODE == 1) v = fmaxf(v, 0.0f);
        const int rr = row + r;
        if constexpr (MODE == 2) {
          const int part = col >> 10, cc = col & 1023, h = cc >> 6, e = cc & 63;
          if (part == 0) v *= 0.18033688011112042f;  // 0.125*log2(e)
          unsigned short* dst = part == 0 ? qb : (part == 1 ? kb : vb);
          dst[(((size_t)((rr >> 11) * 16 + h)) * 2048 + (rr & 2047)) * 64 + e] = f2bf(v);
        } else {
          out[(size_t)rr * N + col] = f2bf(v);
        }
      }
    }
  }
}

// ---------- bf16 GEMM 128x128 (kept for N=1024 cases) ----------
// MODE 0: bf16 out
template <int MODE>
__global__ __launch_bounds__(256, 2) void gemm_bt(
    const unsigned short* __restrict__ A, const unsigned short* __restrict__ Bt,
    const float* __restrict__ bias, unsigned short* __restrict__ out,
    unsigned short* __restrict__ qb, unsigned short* __restrict__ kb,
    unsigned short* __restrict__ vb, int M, int N, int K) {
  __shared__ __align__(16) char As[16384];
  __shared__ __align__(16) char Bs[16384];
  const int tid = threadIdx.x;
  const int wave = tid >> 6, lane = tid & 63;
  const int lrow = lane & 15;
  const int kof = (lane >> 4) * 16;
  const int m0 = blockIdx.y * 128, n0 = blockIdx.x * 128;
  const int wm = (wave >> 1) * 64, wn = (wave & 1) * 64;
  const int chunkrow = lane >> 3;
  const int colb0 = (lane & 7) * 16;

  f32x4 acc[4][4] = {};

  for (int k0 = 0; k0 < K; k0 += 64) {
#pragma unroll
    for (int c = 0; c < 4; ++c) {
      const int chunk = wave * 4 + c;
      const int rowA = chunk * 8 + chunkrow;
      const int srcb = colb0 ^ ((rowA & 7) << 4);
      const char* ga = (const char*)A + ((size_t)(m0 + rowA) * K + k0) * 2 + srcb;
      const char* gb = (const char*)Bt + ((size_t)(n0 + rowA) * K + k0) * 2 + srcb;
      gload_lds16(ga, As + chunk * 1024);
      gload_lds16(gb, Bs + chunk * 1024);
    }
    __syncthreads();
#pragma unroll
    for (int kk = 0; kk < 2; ++kk) {
      bf16x8 af[4], bv4[4];
#pragma unroll
      for (int i = 0; i < 4; ++i) {
        const int ra = wm + i * 16 + lrow;
        af[i] = *(const bf16x8*)(As + ra * 128 + ((kk * 64 + kof) ^ ((ra & 7) << 4)));
        const int rb = wn + i * 16 + lrow;
        bv4[i] = *(const bf16x8*)(Bs + rb * 128 + ((kk * 64 + kof) ^ ((rb & 7) << 4)));
      }
#pragma unroll
      for (int mi = 0; mi < 4; ++mi)
#pragma unroll
        for (int ni = 0; ni < 4; ++ni)
          acc[mi][ni] = __builtin_amdgcn_mfma_f32_16x16x32_bf16(af[mi], bv4[ni], acc[mi][ni], 0, 0, 0);
    }
    __syncthreads();
  }

#pragma unroll
  for (int mi = 0; mi < 4; ++mi) {
    const int row = m0 + wm + mi * 16 + ((lane >> 4) << 2);
#pragma unroll
    for (int ni = 0; ni < 4; ++ni) {
      const int col = n0 + wn + ni * 16 + lrow;
      const float bvv = bias[col];
#pragma unroll
      for (int r = 0; r < 4; ++r) {
        float v = acc[mi][ni][r] + bvv;
        if (MODE == 1) v = fmaxf(v, 0.0f);
        const int rr = row + r;
        out[(size_t)rr * N + col] = f2bf(v);
      }
    }
  }
  (void)qb; (void)kb; (void)vb;
}

// ---------- flash attention v3: swapped 32x32 MFMAs, P stays in registers ----------
__global__ __launch_bounds__(256, 4) void attn_kernel(
    const unsigned short* __restrict__ q_buf, const unsigned short* __restrict__ k_buf,
    const unsigned short* __restrict__ vt_buf, unsigned short* __restrict__ ctx) {
  __shared__ __align__(16) char Ks[2][8192];   // [64 kv][64 d] bf16, swizzled
  __shared__ __align__(16) char Vs[2][8192];   // [64 d][64 kv] bf16, swizzled
  const int tid = threadIdx.x, wave = tid >> 6, lane = tid & 63;
  const int wg = (blockIdx.x & 7) * 128 + (blockIdx.x >> 3);
  const int bh = wg >> 4;
  const int q0 = (wg & 15) * 128;
  const int l31 = lane & 31, hi = lane >> 5;

  bf16x8 qf[4];
#pragma unroll
  for (int kk = 0; kk < 4; ++kk)
    qf[kk] = *(const bf16x8*)(q_buf +
        ((size_t)bh * 2048 + q0 + wave * 32 + l31) * 64 + kk * 16 + hi * 8);

  f32x16 acc_o[2] = {};
  float l_reg = 0.f;

  auto stage = [&](int t, int buf) {
#pragma unroll
    for (int i = 0; i < 2; ++i) {
      const int c = i * 256 + wave * 64 + lane;
      const int row = c >> 3;
      const int col = ((c & 7) * 16) ^ ((row & 7) << 4);
      gload_lds16((const char*)k_buf + ((size_t)(bh * 2048 + t * 64 + row)) * 128 + col,
                  &Ks[buf][(i * 256 + wave * 64) * 16]);
      gload_lds16((const char*)vt_buf + ((size_t)(bh * 64 + row)) * 4096 + t * 128 + col,
                  &Vs[buf][(i * 256 + wave * 64) * 16]);
    }
  };

  stage(0, 0);
  for (int t = 0; t < 32; ++t) {
    const int cur = t & 1;
    __syncthreads();
    stage(t < 31 ? t + 1 : 31, cur ^ 1);

    f32x16 sacc[2] = {};
#pragma unroll
    for (int kk = 0; kk < 4; ++kk) {
      bf16x8 kf[2];
#pragma unroll
      for (int mt = 0; mt < 2; ++mt) {
        const int row = mt * 32 + l31;
        kf[mt] = *(const bf16x8*)&Ks[cur][row * 128 + ((kk * 32 + hi * 16) ^ ((row & 7) << 4))];
      }
      __builtin_amdgcn_s_setprio(1);
#pragma unroll
      for (int mt = 0; mt < 2; ++mt)
        sacc[mt] = __builtin_amdgcn_mfma_f32_32x32x16_bf16(kf[mt], qf[kk], sacc[mt], 0, 0, 0);
      __builtin_amdgcn_s_setprio(0);
    }

#pragma unroll
    for (int mt = 0; mt < 2; ++mt)
#pragma unroll
      for (int r = 0; r < 16; ++r)
        sacc[mt][r] = exp2f(sacc[mt][r]);
    {
      f32x4 s0 = {sacc[0][0], sacc[0][1], sacc[0][2], sacc[0][3]};
      f32x4 s1 = {sacc[0][4], sacc[0][5], sacc[0][6], sacc[0][7]};
      f32x4 s2 = {sacc[0][8], sacc[0][9], sacc[0][10], sacc[0][11]};
      f32x4 s3 = {sacc[0][12], sacc[0][13], sacc[0][14], sacc[0][15]};
#pragma unroll
      for (int r = 0; r < 4; ++r) {
        s0[r] += sacc[1][r];  s1[r] += sacc[1][4 + r];
        s2[r] += sacc[1][8 + r];  s3[r] += sacc[1][12 + r];
      }
      f32x4 s01 = s0 + s1, s23 = s2 + s3;
      f32x4 sa = s01 + s23;
      l_reg += (sa[0] + sa[1]) + (sa[2] + sa[3]);
    }

#pragma unroll
    for (int g = 0; g < 4; ++g) {
      const int m = g >> 1, c = g & 1;
      unsigned w0 = pkbf(sacc[m][8 * c + 0], sacc[m][8 * c + 1]);
      unsigned w1 = pkbf(sacc[m][8 * c + 2], sacc[m][8 * c + 3]);
      unsigned w2 = pkbf(sacc[m][8 * c + 4], sacc[m][8 * c + 5]);
      unsigned w3 = pkbf(sacc[m][8 * c + 6], sacc[m][8 * c + 7]);
      u32x4 bw = {w0, w1, w2, w3};
      bf16x8 pb = __builtin_bit_cast(bf16x8, bw);
      bf16x8 vf[2];
#pragma unroll
      for (int mtd = 0; mtd < 2; ++mtd) {
        const int row = mtd * 32 + l31;
        const int cb = g * 32 + hi * 8;
        const int sw = (row & 7) << 4;
        bf16x4 lo = *(const bf16x4*)&Vs[cur][row * 128 + (cb ^ sw)];
        bf16x4 hi4 = *(const bf16x4*)&Vs[cur][row * 128 + ((cb + 16) ^ sw)];
        vf[mtd] = __builtin_shufflevector(lo, hi4, 0, 1, 2, 3, 4, 5, 6, 7);
      }
      __builtin_amdgcn_s_setprio(1);
#pragma unroll
      for (int mtd = 0; mtd < 2; ++mtd)
        acc_o[mtd] = __builtin_amdgcn_mfma_f32_32x32x16_bf16(vf[mtd], pb, acc_o[mtd], 0, 0, 0);
      __builtin_amdgcn_s_setprio(0);
    }
  }

  const float den = l_reg + __shfl_xor(l_reg, 32);
  const float inv = 1.0f / den;
  const int b = bh >> 4, h = bh & 15;
  const size_t orow = ((size_t)(b * 2048 + q0 + wave * 32 + l31)) * 1024 + h * 64;
#pragma unroll
  for (int mtd = 0; mtd < 2; ++mtd)
#pragma unroll
    for (int gq = 0; gq < 4; ++gq) {
      u16x4 o;
#pragma unroll
      for (int e = 0; e < 4; ++e) o[e] = f2bf(acc_o[mtd][gq * 4 + e] * inv);
      *(u16x4*)(ctx + orow + mtd * 32 + gq * 8 + hi * 4) = o;
    }
}

// ---------- residual + layernorm (block per row, D=1024) ----------
template <bool RES_BF, bool OUT_F32>
__global__ __launch_bounds__(256) void ln_kernel(
    const unsigned short* __restrict__ xin, const void* __restrict__ res,
    const float* __restrict__ g, const float* __restrict__ b, void* __restrict__ out) {
  const int row = blockIdx.x, tid = threadIdx.x;
  const size_t base = (size_t)row * 1024 + tid * 4;
  float x[4];
  u16x4 xv = *(const u16x4*)(xin + base);
  if constexpr (RES_BF) {
    u16x4 rv = *(const u16x4*)((const unsigned short*)res + base);
#pragma unroll
    for (int j = 0; j < 4; ++j) x[j] = bf2f(xv[j]) + bf2f(rv[j]);
  } else {
    f32x4 rv = *(const f32x4*)((const float*)res + base);
#pragma unroll
    for (int j = 0; j < 4; ++j) x[j] = bf2f(xv[j]) + rv[j];
  }
  float s1 = 0.f, s2 = 0.f;
#pragma unroll
  for (int j = 0; j < 4; ++j) { s1 += x[j]; s2 += x[j] * x[j]; }
#pragma unroll
  for (int off = 32; off > 0; off >>= 1) {
    s1 += __shfl_down(s1, off);
    s2 += __shfl_down(s2, off);
  }
  __shared__ float red[8];
  const int wv = tid >> 6, ln = tid & 63;
  if (ln == 0) { red[wv] = s1; red[4 + wv] = s2; }
  __syncthreads();
  s1 = red[0] + red[1] + red[2] + red[3];
  s2 = red[4] + red[5] + red[6] + red[7];
  const float mu = s1 * (1.0f / 1024.0f);
  const float rs = rsqrtf(s2 * (1.0f / 1024.0f) - mu * mu + 1e-5f);
#pragma unroll
  for (int j = 0; j < 4; ++j) {
    const float y = (x[j] - mu) * rs * g[tid * 4 + j] + b[tid * 4 + j];
    if constexpr (OUT_F32) ((float*)out)[base + j] = y;
    else ((unsigned short*)out)[base + j] = f2bf(y);
  }
}

// ---------- workspace layout (bytes) ----------
static const size_t OFF_SBF  = 0;            // 16 MiB (bf16 src) ; reused as h1 later
static const size_t OFF_Q    = 16777216;
static const size_t OFF_K    = 33554432;
static const size_t OFF_V    = 50331648;
static const size_t OFF_VT   = 67108864;
static const size_t OFF_WQKV = 83886080;
static const size_t OFF_BQKV = 90177536;
static const size_t OFF_WO   = 90189824;
static const size_t OFF_W1   = 92286976;
static const size_t OFF_W2   = 100675584;
static const size_t OFF_CTX  = 109064192;
static const size_t OFF_AO   = 125841408;
static const size_t OFF_X1   = 142618624;
static const size_t OFF_FFN  = 159395840;
// total = 176173056 bytes

extern "C" void kernel_launch(void* const* d_in, const int* in_sizes, int n_in,
                              void* d_out, int out_size, void* d_ws, size_t ws_size,
                              hipStream_t stream) {
  const float* src = (const float*)d_in[0];
  const float* Wq  = (const float*)d_in[1];
  const float* bq  = (const float*)d_in[2];
  const float* Wk  = (const float*)d_in[3];
  const float* bk  = (const float*)d_in[4];
  const float* Wv  = (const float*)d_in[5];
  const float* bv  = (const float*)d_in[6];
  const float* Wo  = (const float*)d_in[7];
  const float* bo  = (const float*)d_in[8];
  const float* g1  = (const float*)d_in[9];
  const float* be1 = (const float*)d_in[10];
  const float* W1  = (const float*)d_in[11];
  const float* b1  = (const float*)d_in[12];
  const float* W2  = (const float*)d_in[13];
  const float* b2  = (const float*)d_in[14];
  const float* g2  = (const float*)d_in[15];
  const float* be2 = (const float*)d_in[16];

  char* ws = (char*)d_ws;
  unsigned short* sbf  = (unsigned short*)(ws + OFF_SBF);
  unsigned short* h1   = (unsigned short*)(ws + OFF_SBF);  // alias (sbf/q/k/v dead by then)
  unsigned short* qb   = (unsigned short*)(ws + OFF_Q);
  unsigned short* kb   = (unsigned short*)(ws + OFF_K);
  unsigned short* vb   = (unsigned short*)(ws + OFF_V);
  unsigned short* vtb  = (unsigned short*)(ws + OFF_VT);
  unsigned short* wqkv = (unsigned short*)(ws + OFF_WQKV);
  float*          bqkv = (float*)(ws + OFF_BQKV);
  unsigned short* wot  = (unsigned short*)(ws + OFF_WO);
  unsigned short* w1t  = (unsigned short*)(ws + OFF_W1);
  unsigned short* w2t  = (unsigned short*)(ws + OFF_W2);
  unsigned short* ctx  = (unsigned short*)(ws + OFF_CTX);
  unsigned short* ao   = (unsigned short*)(ws + OFF_AO);
  unsigned short* x1   = (unsigned short*)(ws + OFF_X1);
  unsigned short* ffn  = (unsigned short*)(ws + OFF_FFN);
  float* outp = (float*)d_out;

  // 1) casts / packing
  cvt_f32_bf16<<<dim3(8192), dim3(256), 0, stream>>>(src, sbf, 8388608);
  pack_qkv_w<<<dim3(16, 1, 48), dim3(256), 0, stream>>>(Wq, Wk, Wv, wqkv);
  pack_bias<<<dim3(12), dim3(256), 0, stream>>>(bq, bk, bv, bqkv);
  transpose_cvt<<<dim3(16, 16), dim3(256), 0, stream>>>(Wo, wot, 1024, 1024);
  transpose_cvt<<<dim3(16, 64), dim3(256), 0, stream>>>(W1, w1t, 1024, 4096);
  transpose_cvt<<<dim3(64, 16), dim3(256), 0, stream>>>(W2, w2t, 4096, 1024);

  // 2) QKV projection (fused, 256^2 8-phase): [8192,1024] x [3072,1024]^T
  gemm8<2><<<dim3(384), dim3(512), 0, stream>>>(sbf, wqkv, bqkv, nullptr, qb, kb, vb,
                                                8192, 3072, 1024, 12);
  // 3) V transpose for PV
  vtrans<<<dim3(32, 64), dim3(256), 0, stream>>>(vb, vtb);
  // 4) attention
  attn_kernel<<<dim3(1024), dim3(256), 0, stream>>>(qb, kb, vtb, ctx);
  // 5) output projection (128^2)
  gemm_bt<0><<<dim3(8, 64), dim3(256), 0, stream>>>(ctx, wot, bo, ao, nullptr, nullptr, nullptr,
                                                    8192, 1024, 1024);
  // 6) LN1 (attn_out + src)
  ln_kernel<false, false><<<dim3(8192), dim3(256), 0, stream>>>(ao, src, g1, be1, x1);
  // 7) FFN
  gemm8<1><<<dim3(512), dim3(512), 0, stream>>>(x1, w1t, b1, h1, nullptr, nullptr, nullptr,
                                                8192, 4096, 1024, 16);
  gemm_bt<0><<<dim3(8, 64), dim3(256), 0, stream>>>(h1, w2t, b2, ffn, nullptr, nullptr, nullptr,
                                                    8192, 1024, 4096);
  // 8) LN2 (ffn + x1) -> f32 output
  ln_kernel<true, true><<<dim3(8192), dim3(256), 0, stream>>>(ffn, x1, g2, be2, outp);

  (void)in_sizes; (void)n_in; (void)out_size; (void)ws_size;
}

// Round 5
// 372.835 us; speedup vs baseline: 1.0888x; 1.0888x over previous
//
#include <hip/hip_runtime.h>
#include <stdint.h>

#define DEV __device__ __forceinline__

typedef float f32x4 __attribute__((ext_vector_type(4)));
typedef float f32x16 __attribute__((ext_vector_type(16)));
typedef __bf16 bf16x8 __attribute__((ext_vector_type(8)));
typedef __bf16 bf16x4 __attribute__((ext_vector_type(4)));
typedef unsigned short u16x4 __attribute__((ext_vector_type(4)));
typedef unsigned short u16x8 __attribute__((ext_vector_type(8)));
typedef unsigned u32x4 __attribute__((ext_vector_type(4)));

// ---------- helpers ----------
DEV unsigned short f2bf(float f) {
  unsigned u = __builtin_bit_cast(unsigned, f);
  u += 0x7fffu + ((u >> 16) & 1u);   // RNE
  return (unsigned short)(u >> 16);
}
DEV float bf2f(unsigned short h) {
  unsigned u = ((unsigned)h) << 16;
  return __builtin_bit_cast(float, u);
}
DEV unsigned pkbf(float lo, float hi) {  // D.lo=bf16(S0), D.hi=bf16(S1)
  unsigned r;
  asm("v_cvt_pk_bf16_f32 %0, %1, %2" : "=v"(r) : "v"(lo), "v"(hi));
  return r;
}
DEV float fexp2(float x) {  // raw v_exp_f32: inputs bounded, no denormal guard needed
  float r;
  asm("v_exp_f32 %0, %1" : "=v"(r) : "v"(x));
  return r;
}
DEV void gload_lds16(const void* g, void* l) {
  __builtin_amdgcn_global_load_lds((const __attribute__((address_space(1))) void*)g,
                                   (__attribute__((address_space(3))) void*)l, 16, 0, 0);
}

// ---------- elementwise f32 -> bf16 ----------
__global__ void cvt_f32_bf16(const float* __restrict__ in, unsigned short* __restrict__ out, int n) {
  int i = (blockIdx.x * 256 + threadIdx.x) * 4;
  if (i >= n) return;
  f32x4 v = *(const f32x4*)(in + i);
  u16x4 o;
  o[0] = f2bf(v[0]); o[1] = f2bf(v[1]); o[2] = f2bf(v[2]); o[3] = f2bf(v[3]);
  *(u16x4*)(out + i) = o;
}

// ---------- generic f32 [R][C] -> bf16 [C][R] transpose (64x64 tiles) ----------
__global__ void transpose_cvt(const float* __restrict__ src, unsigned short* __restrict__ dst,
                              int R, int C) {
  __shared__ __align__(16) float t[64][65];
  const int tid = threadIdx.x;
  const int r0 = blockIdx.x * 64, c0 = blockIdx.y * 64;
  const int rr = tid >> 2, q = tid & 3;
  const float* s = src + (size_t)(r0 + rr) * C + c0 + q * 16;
#pragma unroll
  for (int j = 0; j < 4; ++j) {
    f32x4 v = *(const f32x4*)(s + j * 4);
    t[rr][q * 16 + j * 4 + 0] = v[0];
    t[rr][q * 16 + j * 4 + 1] = v[1];
    t[rr][q * 16 + j * 4 + 2] = v[2];
    t[rr][q * 16 + j * 4 + 3] = v[3];
  }
  __syncthreads();
  const int cc = tid >> 2, qq = tid & 3;
  unsigned short* o = dst + (size_t)(c0 + cc) * R + r0 + qq * 16;
  u16x8 a, b;
#pragma unroll
  for (int j = 0; j < 8; ++j) {
    a[j] = f2bf(t[qq * 16 + j][cc]);
    b[j] = f2bf(t[qq * 16 + 8 + j][cc]);
  }
  *(u16x8*)o = a;
  *(u16x8*)(o + 8) = b;
}

// ---------- pack per-head Wq/Wk/Wv [16][1024][64] -> Bt bf16 [3072][1024] ----------
__global__ void pack_qkv_w(const float* __restrict__ Wq, const float* __restrict__ Wk,
                           const float* __restrict__ Wv, unsigned short* __restrict__ dst) {
  __shared__ __align__(16) float t[64][65];
  const int tid = threadIdx.x;
  const int z = blockIdx.z, part = z >> 4, h = z & 15;
  const float* src = (part == 0 ? Wq : (part == 1 ? Wk : Wv)) + (size_t)h * 65536;
  const int r0 = blockIdx.x * 64;  // d tile
  const int rr = tid >> 2, q = tid & 3;
  const float* s = src + (size_t)(r0 + rr) * 64 + q * 16;
#pragma unroll
  for (int j = 0; j < 4; ++j) {
    f32x4 v = *(const f32x4*)(s + j * 4);
    t[rr][q * 16 + j * 4 + 0] = v[0];
    t[rr][q * 16 + j * 4 + 1] = v[1];
    t[rr][q * 16 + j * 4 + 2] = v[2];
    t[rr][q * 16 + j * 4 + 3] = v[3];
  }
  __syncthreads();
  const int cc = tid >> 2, qq = tid & 3;  // cc = e
  unsigned short* o = dst + ((size_t)(part * 1024 + h * 64 + cc)) * 1024 + r0 + qq * 16;
  u16x8 a, b;
#pragma unroll
  for (int j = 0; j < 8; ++j) {
    a[j] = f2bf(t[qq * 16 + j][cc]);
    b[j] = f2bf(t[qq * 16 + 8 + j][cc]);
  }
  *(u16x8*)o = a;
  *(u16x8*)(o + 8) = b;
}

__global__ void pack_bias(const float* __restrict__ bq, const float* __restrict__ bk,
                          const float* __restrict__ bv, float* __restrict__ o) {
  int i = blockIdx.x * 256 + threadIdx.x;  // 0..3071
  o[i] = i < 1024 ? bq[i] : (i < 2048 ? bk[i - 1024] : bv[i - 2048]);
}

// ---------- transpose V [bh][2048][64] -> Vt [bh][64][2048] (bf16) ----------
// kv columns PERMUTED within each 16-group (swap bits 2<->3) so attn's PV
// A-fragment (slots psi(g,hi,j)) is one contiguous b128 read.
__global__ void vtrans(const unsigned short* __restrict__ v, unsigned short* __restrict__ vt) {
  __shared__ __align__(16) unsigned short t[64][72];
  const int tid = threadIdx.x;
  const int bh = blockIdx.y, s0 = blockIdx.x * 64;
  const int r = tid >> 2, q = (tid & 3) * 16;
  const unsigned short* g = v + ((size_t)bh * 2048 + s0 + r) * 64 + q;
  *(u16x8*)&t[r][q] = *(const u16x8*)g;
  *(u16x8*)&t[r][q + 8] = *(const u16x8*)(g + 8);
  __syncthreads();
  const int d = tid >> 2, qq = (tid & 3) * 16;
  unsigned short* o = vt + ((size_t)bh * 64 + d) * 2048 + s0 + qq;
  u16x8 a, b;
#pragma unroll
  for (int j = 0; j < 8; ++j) {
    const int sa = (j & 3) | ((j & 4) << 1);   // 0,1,2,3,8,9,10,11
    a[j] = t[qq + sa][d];
    b[j] = t[qq + sa + 4][d];                  // 4,5,6,7,12,13,14,15
  }
  *(u16x8*)o = a;
  *(u16x8*)(o + 8) = b;
}

// ================= 256x256 8-phase GEMM (T2+T3+T4+T5) =================
// (isolation round: used ONLY for FFN1, grid 512 = exact 2 rounds/CU)
template <int MODE>
__global__ __launch_bounds__(512, 2) void gemm8(
    const unsigned short* __restrict__ A, const unsigned short* __restrict__ Bt,
    const float* __restrict__ bias, unsigned short* __restrict__ out,
    unsigned short* __restrict__ qb, unsigned short* __restrict__ kb,
    unsigned short* __restrict__ vb, int M, int N, int K, int NBN) {
  __shared__ __align__(16) char As[2][32768];
  __shared__ __align__(16) char Bs[2][32768];
  const int tid = threadIdx.x, wave = tid >> 6, lane = tid & 63;
  const int lrow = lane & 15, lgk = (lane >> 4) * 16;
  const int cr = lane >> 3;
  const int csw = ((lane & 7) * 16) ^ (cr << 4);
  const int nwg = gridDim.x, bid = blockIdx.x;
  const int wg = (bid & 7) * (nwg >> 3) + (bid >> 3);   // bijective (nwg%8==0)
  const int bm = wg / NBN, bn = wg % NBN;
  const int m0 = bm * 256, n0 = bn * 256;
  const int wm = (wave >> 2) * 128, wn = (wave & 3) * 64;
  const char* Ab = (const char*)A;
  const char* Bb = (const char*)Bt;
  const int NT = K >> 6;

  f32x4 acc[8][4] = {};
  bf16x8 af[4][2];
  bf16x8 bf0[2][2], bf1[2][2];

#define ISSUE_A(kt, half) do {                                                \
    _Pragma("unroll") for (int rep = 0; rep < 2; ++rep) {                     \
      const int j = wave * 2 + rep;                                           \
      const int row0 = j * 8 + ((j >= 8) ? 64 : 0) + (half) * 64;             \
      gload_lds16(Ab + (((size_t)(m0 + row0 + cr) * K + (kt) * 64) << 1) + csw,\
                  &As[(kt) & 1][row0 * 128]);                                 \
    } } while (0)
#define ISSUE_B(kt, half) do {                                                \
    _Pragma("unroll") for (int rep = 0; rep < 2; ++rep) {                     \
      const int j = wave * 2 + rep;                                           \
      const int row0 = (j >> 2) * 64 + (j & 3) * 8 + (half) * 32;             \
      gload_lds16(Bb + (((size_t)(n0 + row0 + cr) * K + (kt) * 64) << 1) + csw,\
                  &Bs[(kt) & 1][row0 * 128]);                                 \
    } } while (0)
#define READ_A(dbuf, mh) do {                                                 \
    _Pragma("unroll") for (int i = 0; i < 4; ++i) {                           \
      const int row = wm + ((mh) * 4 + i) * 16 + lrow;                        \
      const int sw = (row & 7) << 4;                                          \
      af[i][0] = *(const bf16x8*)&As[dbuf][row * 128 + (lgk ^ sw)];           \
      af[i][1] = *(const bf16x8*)&As[dbuf][row * 128 + ((64 + lgk) ^ sw)];    \
    } } while (0)
#define READ_B(dbuf, nh, bfx) do {                                            \
    _Pragma("unroll") for (int i = 0; i < 2; ++i) {                           \
      const int row = wn + ((nh) * 2 + i) * 16 + lrow;                        \
      const int sw = (row & 7) << 4;                                          \
      bfx[i][0] = *(const bf16x8*)&Bs[dbuf][row * 128 + (lgk ^ sw)];          \
      bfx[i][1] = *(const bf16x8*)&Bs[dbuf][row * 128 + ((64 + lgk) ^ sw)];   \
    } } while (0)
#define MFMA_Q(mh, nh, bfx) do {                                              \
    __builtin_amdgcn_s_setprio(1);                                            \
    _Pragma("unroll") for (int i = 0; i < 4; ++i)                             \
    _Pragma("unroll") for (int n = 0; n < 2; ++n)                             \
    _Pragma("unroll") for (int kk = 0; kk < 2; ++kk)                          \
      acc[(mh) * 4 + i][(nh) * 2 + n] = __builtin_amdgcn_mfma_f32_16x16x32_bf16(\
          af[i][kk], bfx[n][kk], acc[(mh) * 4 + i][(nh) * 2 + n], 0, 0, 0);   \
    __builtin_amdgcn_s_setprio(0);                                            \
  } while (0)
#define BAR() __builtin_amdgcn_s_barrier()
#define LGKM0() do { asm volatile("s_waitcnt lgkmcnt(0)" ::: "memory");       \
    __builtin_amdgcn_sched_barrier(0); } while (0)
#define VMCNT6() asm volatile("s_waitcnt vmcnt(6)" ::: "memory")
#define VMCNT0() asm volatile("s_waitcnt vmcnt(0)" ::: "memory")

  ISSUE_A(0, 0); ISSUE_B(0, 0); ISSUE_B(0, 1); ISSUE_A(0, 1);
  __syncthreads();
  ISSUE_A(1, 0); ISSUE_B(1, 0); ISSUE_B(1, 1);

  for (int a = 0; a < NT; a += 2) {
    const int d0 = a & 1, d1 = d0 ^ 1;
    const bool g2 = (a + 2) < NT, g3 = (a + 3) < NT;
    // ---- tile a ----
    READ_A(d0, 0); READ_B(d0, 0, bf0);
    ISSUE_A(a + 1, 1);
    BAR(); LGKM0();
    MFMA_Q(0, 0, bf0);
    BAR();
    READ_B(d0, 1, bf1);
    if (g2) ISSUE_A(a + 2, 0);
    BAR(); LGKM0();
    MFMA_Q(0, 1, bf1);
    BAR();
    READ_A(d0, 1);
    if (g2) ISSUE_B(a + 2, 0);
    BAR(); LGKM0();
    MFMA_Q(1, 0, bf0);
    BAR();
    if (g2) { ISSUE_B(a + 2, 1); VMCNT6(); } else { VMCNT0(); }
    BAR();
    MFMA_Q(1, 1, bf1);
    BAR();
    // ---- tile a+1 ----
    READ_A(d1, 0); READ_B(d1, 0, bf0);
    if (g2) ISSUE_A(a + 2, 1);
    BAR(); LGKM0();
    MFMA_Q(0, 0, bf0);
    BAR();
    READ_B(d1, 1, bf1);
    if (g3) ISSUE_A(a + 3, 0);
    BAR(); LGKM0();
    MFMA_Q(0, 1, bf1);
    BAR();
    READ_A(d1, 1);
    if (g3) ISSUE_B(a + 3, 0);
    BAR(); LGKM0();
    MFMA_Q(1, 0, bf0);
    BAR();
    if (g3) { ISSUE_B(a + 3, 1); VMCNT6(); } else { VMCNT0(); }
    BAR();
    MFMA_Q(1, 1, bf1);
    BAR();
  }
#undef ISSUE_A
#undef ISSUE_B
#undef READ_A
#undef READ_B
#undef MFMA_Q
#undef BAR
#undef LGKM0
#undef VMCNT6
#undef VMCNT0

#pragma unroll
  for (int mi = 0; mi < 8; ++mi) {
    const int row = m0 + wm + mi * 16 + ((lane >> 4) << 2);
#pragma unroll
    for (int ni = 0; ni < 4; ++ni) {
      const int col = n0 + wn + ni * 16 + lrow;
      const float bvv = bias[col];
#pragma unroll
      for (int r = 0; r < 4; ++r) {
        float v = acc[mi][ni][r] + bvv;
        if (MODE == 1) v = fmaxf(v, 0.0f);
        const int rr = row + r;
        if constexpr (MODE == 2) {
          const int part = col >> 10, cc = col & 1023, h = cc >> 6, e = cc & 63;
          if (part == 0) v *= 0.18033688011112042f;
          unsigned short* dst = part == 0 ? qb : (part == 1 ? kb : vb);
          dst[(((size_t)((rr >> 11) * 16 + h)) * 2048 + (rr & 2047)) * 64 + e] = f2bf(v);
        } else {
          out[(size_t)rr * N + col] = f2bf(v);
        }
      }
    }
  }
}

// ---------- bf16 GEMM 128x128: out[M][N] = A[M][K]*Bt[N][K]^T + bias ----------
// MODE 0: bf16 out, 1: +relu, 2: split q/k/v (+q pre-scale 0.125*log2e)
template <int MODE>
__global__ __launch_bounds__(256, 2) void gemm_bt(
    const unsigned short* __restrict__ A, const unsigned short* __restrict__ Bt,
    const float* __restrict__ bias, unsigned short* __restrict__ out,
    unsigned short* __restrict__ qb, unsigned short* __restrict__ kb,
    unsigned short* __restrict__ vb, int M, int N, int K) {
  __shared__ __align__(16) char As[16384];
  __shared__ __align__(16) char Bs[16384];
  const int tid = threadIdx.x;
  const int wave = tid >> 6, lane = tid & 63;
  const int lrow = lane & 15;
  const int kof = (lane >> 4) * 16;
  const int m0 = blockIdx.y * 128, n0 = blockIdx.x * 128;
  const int wm = (wave >> 1) * 64, wn = (wave & 1) * 64;
  const int chunkrow = lane >> 3;
  const int colb0 = (lane & 7) * 16;

  f32x4 acc[4][4] = {};

  for (int k0 = 0; k0 < K; k0 += 64) {
#pragma unroll
    for (int c = 0; c < 4; ++c) {
      const int chunk = wave * 4 + c;
      const int rowA = chunk * 8 + chunkrow;
      const int srcb = colb0 ^ ((rowA & 7) << 4);
      const char* ga = (const char*)A + ((size_t)(m0 + rowA) * K + k0) * 2 + srcb;
      const char* gb = (const char*)Bt + ((size_t)(n0 + rowA) * K + k0) * 2 + srcb;
      gload_lds16(ga, As + chunk * 1024);
      gload_lds16(gb, Bs + chunk * 1024);
    }
    __syncthreads();
#pragma unroll
    for (int kk = 0; kk < 2; ++kk) {
      bf16x8 af[4], bv4[4];
#pragma unroll
      for (int i = 0; i < 4; ++i) {
        const int ra = wm + i * 16 + lrow;
        af[i] = *(const bf16x8*)(As + ra * 128 + ((kk * 64 + kof) ^ ((ra & 7) << 4)));
        const int rb = wn + i * 16 + lrow;
        bv4[i] = *(const bf16x8*)(Bs + rb * 128 + ((kk * 64 + kof) ^ ((rb & 7) << 4)));
      }
#pragma unroll
      for (int mi = 0; mi < 4; ++mi)
#pragma unroll
        for (int ni = 0; ni < 4; ++ni)
          acc[mi][ni] = __builtin_amdgcn_mfma_f32_16x16x32_bf16(af[mi], bv4[ni], acc[mi][ni], 0, 0, 0);
    }
    __syncthreads();
  }

#pragma unroll
  for (int mi = 0; mi < 4; ++mi) {
    const int row = m0 + wm + mi * 16 + ((lane >> 4) << 2);
#pragma unroll
    for (int ni = 0; ni < 4; ++ni) {
      const int col = n0 + wn + ni * 16 + lrow;
      const float bvv = bias[col];
#pragma unroll
      for (int r = 0; r < 4; ++r) {
        float v = acc[mi][ni][r] + bvv;
        if (MODE == 1) v = fmaxf(v, 0.0f);
        const int rr = row + r;
        if constexpr (MODE == 2) {
          const int part = col >> 10, cc = col & 1023, h = cc >> 6, e = cc & 63;
          if (part == 0) v *= 0.18033688011112042f;  // 0.125*log2(e)
          unsigned short* dst = part == 0 ? qb : (part == 1 ? kb : vb);
          dst[(((size_t)((rr >> 11) * 16 + h)) * 2048 + (rr & 2047)) * 64 + e] = f2bf(v);
        } else {
          out[(size_t)rr * N + col] = f2bf(v);
        }
      }
    }
  }
}

// ---------- flash attention v4: raw exp, MFMA denominator, b128 V-frags ----------
__global__ __launch_bounds__(256, 4) void attn_kernel(
    const unsigned short* __restrict__ q_buf, const unsigned short* __restrict__ k_buf,
    const unsigned short* __restrict__ vt_buf, unsigned short* __restrict__ ctx) {
  __shared__ __align__(16) char Ks[2][8192];   // [64 kv][64 d] bf16, swizzled
  __shared__ __align__(16) char Vs[2][8192];   // [64 d][64 kv(perm)] bf16, swizzled
  const int tid = threadIdx.x, wave = tid >> 6, lane = tid & 63;
  const int wg = (blockIdx.x & 7) * 128 + (blockIdx.x >> 3);
  const int bh = wg >> 4;
  const int q0 = (wg & 15) * 128;
  const int l31 = lane & 31, hi = lane >> 5;

  bf16x8 qf[4];
#pragma unroll
  for (int kk = 0; kk < 4; ++kk)
    qf[kk] = *(const bf16x8*)(q_buf +
        ((size_t)bh * 2048 + q0 + wave * 32 + l31) * 64 + kk * 16 + hi * 8);

  f32x16 acc_o[2] = {};
  f32x16 accd = {};
  bf16x8 ones;
#pragma unroll
  for (int j = 0; j < 8; ++j) ones[j] = (__bf16)1.0f;

  auto stage = [&](int t, int buf) {
#pragma unroll
    for (int i = 0; i < 2; ++i) {
      const int c = i * 256 + wave * 64 + lane;
      const int row = c >> 3;
      const int col = ((c & 7) * 16) ^ ((row & 7) << 4);
      gload_lds16((const char*)k_buf + ((size_t)(bh * 2048 + t * 64 + row)) * 128 + col,
                  &Ks[buf][(i * 256 + wave * 64) * 16]);
      gload_lds16((const char*)vt_buf + ((size_t)(bh * 64 + row)) * 4096 + t * 128 + col,
                  &Vs[buf][(i * 256 + wave * 64) * 16]);
    }
  };

  stage(0, 0);
  for (int t = 0; t < 32; ++t) {
    const int cur = t & 1;
    __syncthreads();
    stage(t < 31 ? t + 1 : 31, cur ^ 1);

    // S^T = K * Q^T (M=64 kv via 2 m-tiles, N=32 q, K=64 d)
    f32x16 sacc[2] = {};
#pragma unroll
    for (int kk = 0; kk < 4; ++kk) {
      bf16x8 kf[2];
#pragma unroll
      for (int mt = 0; mt < 2; ++mt) {
        const int row = mt * 32 + l31;
        kf[mt] = *(const bf16x8*)&Ks[cur][row * 128 + ((kk * 32 + hi * 16) ^ ((row & 7) << 4))];
      }
      __builtin_amdgcn_s_setprio(1);
#pragma unroll
      for (int mt = 0; mt < 2; ++mt)
        sacc[mt] = __builtin_amdgcn_mfma_f32_32x32x16_bf16(kf[mt], qf[kk], sacc[mt], 0, 0, 0);
      __builtin_amdgcn_s_setprio(0);
    }

    // p = 2^s in place (scale folded into Q); no guard (bounded inputs)
#pragma unroll
    for (int mt = 0; mt < 2; ++mt)
#pragma unroll
      for (int r = 0; r < 16; ++r)
        sacc[mt][r] = fexp2(sacc[mt][r]);

    // O^T += V^T * P^T ; den += ones * P^T (on MFMA pipe).
    // Sub-MFMA g: kv = 32(g>>1)+16(g&1)+8(j>>2)+4hi+(j&3); Vt pre-permuted so
    // V-frag = one b128 at phys col 16g+8hi.
#pragma unroll
    for (int g = 0; g < 4; ++g) {
      const int m = g >> 1, c = g & 1;
      unsigned w0 = pkbf(sacc[m][8 * c + 0], sacc[m][8 * c + 1]);
      unsigned w1 = pkbf(sacc[m][8 * c + 2], sacc[m][8 * c + 3]);
      unsigned w2 = pkbf(sacc[m][8 * c + 4], sacc[m][8 * c + 5]);
      unsigned w3 = pkbf(sacc[m][8 * c + 6], sacc[m][8 * c + 7]);
      u32x4 bw = {w0, w1, w2, w3};
      bf16x8 pb = __builtin_bit_cast(bf16x8, bw);
      bf16x8 vf[2];
#pragma unroll
      for (int mtd = 0; mtd < 2; ++mtd) {
        const int row = mtd * 32 + l31;
        const int sw = (row & 7) << 4;
        vf[mtd] = *(const bf16x8*)&Vs[cur][row * 128 + ((g * 32 + hi * 16) ^ sw)];
      }
      __builtin_amdgcn_s_setprio(1);
      accd = __builtin_amdgcn_mfma_f32_32x32x16_bf16(ones, pb, accd, 0, 0, 0);
#pragma unroll
      for (int mtd = 0; mtd < 2; ++mtd)
        acc_o[mtd] = __builtin_amdgcn_mfma_f32_32x32x16_bf16(vf[mtd], pb, acc_o[mtd], 0, 0, 0);
      __builtin_amdgcn_s_setprio(0);
    }
  }

  // accd rows are all identical (ones A); K-dim spanned both lane halves ->
  // accd[0] = full denominator for q = l31, no cross-lane needed.
  const float inv = 1.0f / accd[0];
  const int b = bh >> 4, h = bh & 15;
  const size_t orow = ((size_t)(b * 2048 + q0 + wave * 32 + l31)) * 1024 + h * 64;
#pragma unroll
  for (int mtd = 0; mtd < 2; ++mtd)
#pragma unroll
    for (int gq = 0; gq < 4; ++gq) {
      u16x4 o;
#pragma unroll
      for (int e = 0; e < 4; ++e) o[e] = f2bf(acc_o[mtd][gq * 4 + e] * inv);
      *(u16x4*)(ctx + orow + mtd * 32 + gq * 8 + hi * 4) = o;
    }
}

// ---------- residual + layernorm (block per row, D=1024) ----------
template <bool RES_BF, bool OUT_F32>
__global__ __launch_bounds__(256) void ln_kernel(
    const unsigned short* __restrict__ xin, const void* __restrict__ res,
    const float* __restrict__ g, const float* __restrict__ b, void* __restrict__ out) {
  const int row = blockIdx.x, tid = threadIdx.x;
  const size_t base = (size_t)row * 1024 + tid * 4;
  float x[4];
  u16x4 xv = *(const u16x4*)(xin + base);
  if constexpr (RES_BF) {
    u16x4 rv = *(const u16x4*)((const unsigned short*)res + base);
#pragma unroll
    for (int j = 0; j < 4; ++j) x[j] = bf2f(xv[j]) + bf2f(rv[j]);
  } else {
    f32x4 rv = *(const f32x4*)((const float*)res + base);
#pragma unroll
    for (int j = 0; j < 4; ++j) x[j] = bf2f(xv[j]) + rv[j];
  }
  float s1 = 0.f, s2 = 0.f;
#pragma unroll
  for (int j = 0; j < 4; ++j) { s1 += x[j]; s2 += x[j] * x[j]; }
#pragma unroll
  for (int off = 32; off > 0; off >>= 1) {
    s1 += __shfl_down(s1, off);
    s2 += __shfl_down(s2, off);
  }
  __shared__ float red[8];
  const int wv = tid >> 6, ln = tid & 63;
  if (ln == 0) { red[wv] = s1; red[4 + wv] = s2; }
  __syncthreads();
  s1 = red[0] + red[1] + red[2] + red[3];
  s2 = red[4] + red[5] + red[6] + red[7];
  const float mu = s1 * (1.0f / 1024.0f);
  const float rs = rsqrtf(s2 * (1.0f / 1024.0f) - mu * mu + 1e-5f);
#pragma unroll
  for (int j = 0; j < 4; ++j) {
    const float y = (x[j] - mu) * rs * g[tid * 4 + j] + b[tid * 4 + j];
    if constexpr (OUT_F32) ((float*)out)[base + j] = y;
    else ((unsigned short*)out)[base + j] = f2bf(y);
  }
}

// ---------- workspace layout (bytes) ----------
static const size_t OFF_SBF  = 0;            // 16 MiB (bf16 src) ; reused as h1 later
static const size_t OFF_Q    = 16777216;
static const size_t OFF_K    = 33554432;
static const size_t OFF_V    = 50331648;
static const size_t OFF_VT   = 67108864;
static const size_t OFF_WQKV = 83886080;
static const size_t OFF_BQKV = 90177536;
static const size_t OFF_WO   = 90189824;
static const size_t OFF_W1   = 92286976;
static const size_t OFF_W2   = 100675584;
static const size_t OFF_CTX  = 109064192;
static const size_t OFF_AO   = 125841408;
static const size_t OFF_X1   = 142618624;
static const size_t OFF_FFN  = 159395840;
// total = 176173056 bytes

extern "C" void kernel_launch(void* const* d_in, const int* in_sizes, int n_in,
                              void* d_out, int out_size, void* d_ws, size_t ws_size,
                              hipStream_t stream) {
  const float* src = (const float*)d_in[0];
  const float* Wq  = (const float*)d_in[1];
  const float* bq  = (const float*)d_in[2];
  const float* Wk  = (const float*)d_in[3];
  const float* bk  = (const float*)d_in[4];
  const float* Wv  = (const float*)d_in[5];
  const float* bv  = (const float*)d_in[6];
  const float* Wo  = (const float*)d_in[7];
  const float* bo  = (const float*)d_in[8];
  const float* g1  = (const float*)d_in[9];
  const float* be1 = (const float*)d_in[10];
  const float* W1  = (const float*)d_in[11];
  const float* b1  = (const float*)d_in[12];
  const float* W2  = (const float*)d_in[13];
  const float* b2  = (const float*)d_in[14];
  const float* g2  = (const float*)d_in[15];
  const float* be2 = (const float*)d_in[16];

  char* ws = (char*)d_ws;
  unsigned short* sbf  = (unsigned short*)(ws + OFF_SBF);
  unsigned short* h1   = (unsigned short*)(ws + OFF_SBF);  // alias (sbf/q/k/v dead by then)
  unsigned short* qb   = (unsigned short*)(ws + OFF_Q);
  unsigned short* kb   = (unsigned short*)(ws + OFF_K);
  unsigned short* vb   = (unsigned short*)(ws + OFF_V);
  unsigned short* vtb  = (unsigned short*)(ws + OFF_VT);
  unsigned short* wqkv = (unsigned short*)(ws + OFF_WQKV);
  float*          bqkv = (float*)(ws + OFF_BQKV);
  unsigned short* wot  = (unsigned short*)(ws + OFF_WO);
  unsigned short* w1t  = (unsigned short*)(ws + OFF_W1);
  unsigned short* w2t  = (unsigned short*)(ws + OFF_W2);
  unsigned short* ctx  = (unsigned short*)(ws + OFF_CTX);
  unsigned short* ao   = (unsigned short*)(ws + OFF_AO);
  unsigned short* x1   = (unsigned short*)(ws + OFF_X1);
  unsigned short* ffn  = (unsigned short*)(ws + OFF_FFN);
  float* outp = (float*)d_out;

  // 1) casts / packing
  cvt_f32_bf16<<<dim3(8192), dim3(256), 0, stream>>>(src, sbf, 8388608);
  pack_qkv_w<<<dim3(16, 1, 48), dim3(256), 0, stream>>>(Wq, Wk, Wv, wqkv);
  pack_bias<<<dim3(12), dim3(256), 0, stream>>>(bq, bk, bv, bqkv);
  transpose_cvt<<<dim3(16, 16), dim3(256), 0, stream>>>(Wo, wot, 1024, 1024);
  transpose_cvt<<<dim3(16, 64), dim3(256), 0, stream>>>(W1, w1t, 1024, 4096);
  transpose_cvt<<<dim3(64, 16), dim3(256), 0, stream>>>(W2, w2t, 4096, 1024);

  // 2) QKV projection (128^2, reverted): [8192,1024] x [3072,1024]^T
  gemm_bt<2><<<dim3(24, 64), dim3(256), 0, stream>>>(sbf, wqkv, bqkv, nullptr, qb, kb, vb,
                                                     8192, 3072, 1024);
  // 3) V transpose (kv-permuted) for PV
  vtrans<<<dim3(32, 64), dim3(256), 0, stream>>>(vb, vtb);
  // 4) attention
  attn_kernel<<<dim3(1024), dim3(256), 0, stream>>>(qb, kb, vtb, ctx);
  // 5) output projection (128^2)
  gemm_bt<0><<<dim3(8, 64), dim3(256), 0, stream>>>(ctx, wot, bo, ao, nullptr, nullptr, nullptr,
                                                    8192, 1024, 1024);
  // 6) LN1 (attn_out + src)
  ln_kernel<false, false><<<dim3(8192), dim3(256), 0, stream>>>(ao, src, g1, be1, x1);
  // 7) FFN (FFN1 on 8-phase — isolation; FFN2 on 128^2)
  gemm8<1><<<dim3(512), dim3(512), 0, stream>>>(x1, w1t, b1, h1, nullptr, nullptr, nullptr,
                                                8192, 4096, 1024, 16);
  gemm_bt<0><<<dim3(8, 64), dim3(256), 0, stream>>>(h1, w2t, b2, ffn, nullptr, nullptr, nullptr,
                                                    8192, 1024, 4096);
  // 8) LN2 (ffn + x1) -> f32 output
  ln_kernel<true, true><<<dim3(8192), dim3(256), 0, stream>>>(ffn, x1, g2, be2, outp);

  (void)in_sizes; (void)n_in; (void)out_size; (void)ws_size;
}

// Round 6
// 372.591 us; speedup vs baseline: 1.0896x; 1.0007x over previous
//
#include <hip/hip_runtime.h>
#include <stdint.h>

#define DEV __device__ __forceinline__

typedef float f32x4 __attribute__((ext_vector_type(4)));
typedef float f32x16 __attribute__((ext_vector_type(16)));
typedef __bf16 bf16x8 __attribute__((ext_vector_type(8)));
typedef __bf16 bf16x4 __attribute__((ext_vector_type(4)));
typedef unsigned short u16x4 __attribute__((ext_vector_type(4)));
typedef unsigned short u16x8 __attribute__((ext_vector_type(8)));
typedef unsigned u32x4 __attribute__((ext_vector_type(4)));

// ---------- helpers ----------
DEV unsigned short f2bf(float f) {
  unsigned u = __builtin_bit_cast(unsigned, f);
  u += 0x7fffu + ((u >> 16) & 1u);   // RNE
  return (unsigned short)(u >> 16);
}
DEV float bf2f(unsigned short h) {
  unsigned u = ((unsigned)h) << 16;
  return __builtin_bit_cast(float, u);
}
DEV unsigned pkbf(float lo, float hi) {  // D.lo=bf16(S0), D.hi=bf16(S1)
  unsigned r;
  asm("v_cvt_pk_bf16_f32 %0, %1, %2" : "=v"(r) : "v"(lo), "v"(hi));
  return r;
}
DEV float fexp2(float x) {  // raw v_exp_f32: inputs bounded, no denormal guard needed
  float r;
  asm("v_exp_f32 %0, %1" : "=v"(r) : "v"(x));
  return r;
}
DEV void gload_lds16(const void* g, void* l) {
  __builtin_amdgcn_global_load_lds((const __attribute__((address_space(1))) void*)g,
                                   (__attribute__((address_space(3))) void*)l, 16, 0, 0);
}

// ---------- elementwise f32 -> bf16 ----------
__global__ void cvt_f32_bf16(const float* __restrict__ in, unsigned short* __restrict__ out, int n) {
  int i = (blockIdx.x * 256 + threadIdx.x) * 4;
  if (i >= n) return;
  f32x4 v = *(const f32x4*)(in + i);
  u16x4 o;
  o[0] = f2bf(v[0]); o[1] = f2bf(v[1]); o[2] = f2bf(v[2]); o[3] = f2bf(v[3]);
  *(u16x4*)(out + i) = o;
}

// ---------- generic f32 [R][C] -> bf16 [C][R] transpose (64x64 tiles) ----------
__global__ void transpose_cvt(const float* __restrict__ src, unsigned short* __restrict__ dst,
                              int R, int C) {
  __shared__ __align__(16) float t[64][65];
  const int tid = threadIdx.x;
  const int r0 = blockIdx.x * 64, c0 = blockIdx.y * 64;
  const int rr = tid >> 2, q = tid & 3;
  const float* s = src + (size_t)(r0 + rr) * C + c0 + q * 16;
#pragma unroll
  for (int j = 0; j < 4; ++j) {
    f32x4 v = *(const f32x4*)(s + j * 4);
    t[rr][q * 16 + j * 4 + 0] = v[0];
    t[rr][q * 16 + j * 4 + 1] = v[1];
    t[rr][q * 16 + j * 4 + 2] = v[2];
    t[rr][q * 16 + j * 4 + 3] = v[3];
  }
  __syncthreads();
  const int cc = tid >> 2, qq = tid & 3;
  unsigned short* o = dst + (size_t)(c0 + cc) * R + r0 + qq * 16;
  u16x8 a, b;
#pragma unroll
  for (int j = 0; j < 8; ++j) {
    a[j] = f2bf(t[qq * 16 + j][cc]);
    b[j] = f2bf(t[qq * 16 + 8 + j][cc]);
  }
  *(u16x8*)o = a;
  *(u16x8*)(o + 8) = b;
}

// ---------- pack per-head Wq/Wk/Wv [16][1024][64] -> Bt bf16 [3072][1024] ----------
__global__ void pack_qkv_w(const float* __restrict__ Wq, const float* __restrict__ Wk,
                           const float* __restrict__ Wv, unsigned short* __restrict__ dst) {
  __shared__ __align__(16) float t[64][65];
  const int tid = threadIdx.x;
  const int z = blockIdx.z, part = z >> 4, h = z & 15;
  const float* src = (part == 0 ? Wq : (part == 1 ? Wk : Wv)) + (size_t)h * 65536;
  const int r0 = blockIdx.x * 64;  // d tile
  const int rr = tid >> 2, q = tid & 3;
  const float* s = src + (size_t)(r0 + rr) * 64 + q * 16;
#pragma unroll
  for (int j = 0; j < 4; ++j) {
    f32x4 v = *(const f32x4*)(s + j * 4);
    t[rr][q * 16 + j * 4 + 0] = v[0];
    t[rr][q * 16 + j * 4 + 1] = v[1];
    t[rr][q * 16 + j * 4 + 2] = v[2];
    t[rr][q * 16 + j * 4 + 3] = v[3];
  }
  __syncthreads();
  const int cc = tid >> 2, qq = tid & 3;  // cc = e
  unsigned short* o = dst + ((size_t)(part * 1024 + h * 64 + cc)) * 1024 + r0 + qq * 16;
  u16x8 a, b;
#pragma unroll
  for (int j = 0; j < 8; ++j) {
    a[j] = f2bf(t[qq * 16 + j][cc]);
    b[j] = f2bf(t[qq * 16 + 8 + j][cc]);
  }
  *(u16x8*)o = a;
  *(u16x8*)(o + 8) = b;
}

__global__ void pack_bias(const float* __restrict__ bq, const float* __restrict__ bk,
                          const float* __restrict__ bv, float* __restrict__ o) {
  int i = blockIdx.x * 256 + threadIdx.x;  // 0..3071
  o[i] = i < 1024 ? bq[i] : (i < 2048 ? bk[i - 1024] : bv[i - 2048]);
}

// ---------- transpose V [bh][2048][64] -> Vt [bh][64][2048] (bf16) ----------
// kv columns PERMUTED within each 16-group (swap bits 2<->3) so attn's PV
// A-fragment (slots psi(g,hi,j)) is one contiguous b128 read.
__global__ void vtrans(const unsigned short* __restrict__ v, unsigned short* __restrict__ vt) {
  __shared__ __align__(16) unsigned short t[64][72];
  const int tid = threadIdx.x;
  const int bh = blockIdx.y, s0 = blockIdx.x * 64;
  const int r = tid >> 2, q = (tid & 3) * 16;
  const unsigned short* g = v + ((size_t)bh * 2048 + s0 + r) * 64 + q;
  *(u16x8*)&t[r][q] = *(const u16x8*)g;
  *(u16x8*)&t[r][q + 8] = *(const u16x8*)(g + 8);
  __syncthreads();
  const int d = tid >> 2, qq = (tid & 3) * 16;
  unsigned short* o = vt + ((size_t)bh * 64 + d) * 2048 + s0 + qq;
  u16x8 a, b;
#pragma unroll
  for (int j = 0; j < 8; ++j) {
    const int sa = (j & 3) | ((j & 4) << 1);   // 0,1,2,3,8,9,10,11
    a[j] = t[qq + sa][d];
    b[j] = t[qq + sa + 4][d];                  // 4,5,6,7,12,13,14,15
  }
  *(u16x8*)o = a;
  *(u16x8*)(o + 8) = b;
}

// ================= 256x256 8-phase GEMM (T2+T3+T4+T5) =================
// v2: MFMA kk-loop hoisted OUTER (H8 fix) — consecutive MFMAs now hit 8
// distinct accumulators instead of dependent back-to-back pairs.
template <int MODE>
__global__ __launch_bounds__(512, 2) void gemm8(
    const unsigned short* __restrict__ A, const unsigned short* __restrict__ Bt,
    const float* __restrict__ bias, unsigned short* __restrict__ out,
    unsigned short* __restrict__ qb, unsigned short* __restrict__ kb,
    unsigned short* __restrict__ vb, int M, int N, int K, int NBN) {
  __shared__ __align__(16) char As[2][32768];
  __shared__ __align__(16) char Bs[2][32768];
  const int tid = threadIdx.x, wave = tid >> 6, lane = tid & 63;
  const int lrow = lane & 15, lgk = (lane >> 4) * 16;
  const int cr = lane >> 3;
  const int csw = ((lane & 7) * 16) ^ (cr << 4);
  const int nwg = gridDim.x, bid = blockIdx.x;
  const int wg = (bid & 7) * (nwg >> 3) + (bid >> 3);   // bijective (nwg%8==0)
  const int bm = wg / NBN, bn = wg % NBN;
  const int m0 = bm * 256, n0 = bn * 256;
  const int wm = (wave >> 2) * 128, wn = (wave & 3) * 64;
  const char* Ab = (const char*)A;
  const char* Bb = (const char*)Bt;
  const int NT = K >> 6;

  f32x4 acc[8][4] = {};
  bf16x8 af[4][2];
  bf16x8 bf0[2][2], bf1[2][2];

#define ISSUE_A(kt, half) do {                                                \
    _Pragma("unroll") for (int rep = 0; rep < 2; ++rep) {                     \
      const int j = wave * 2 + rep;                                           \
      const int row0 = j * 8 + ((j >= 8) ? 64 : 0) + (half) * 64;             \
      gload_lds16(Ab + (((size_t)(m0 + row0 + cr) * K + (kt) * 64) << 1) + csw,\
                  &As[(kt) & 1][row0 * 128]);                                 \
    } } while (0)
#define ISSUE_B(kt, half) do {                                                \
    _Pragma("unroll") for (int rep = 0; rep < 2; ++rep) {                     \
      const int j = wave * 2 + rep;                                           \
      const int row0 = (j >> 2) * 64 + (j & 3) * 8 + (half) * 32;             \
      gload_lds16(Bb + (((size_t)(n0 + row0 + cr) * K + (kt) * 64) << 1) + csw,\
                  &Bs[(kt) & 1][row0 * 128]);                                 \
    } } while (0)
#define READ_A(dbuf, mh) do {                                                 \
    _Pragma("unroll") for (int i = 0; i < 4; ++i) {                           \
      const int row = wm + ((mh) * 4 + i) * 16 + lrow;                        \
      const int sw = (row & 7) << 4;                                          \
      af[i][0] = *(const bf16x8*)&As[dbuf][row * 128 + (lgk ^ sw)];           \
      af[i][1] = *(const bf16x8*)&As[dbuf][row * 128 + ((64 + lgk) ^ sw)];    \
    } } while (0)
#define READ_B(dbuf, nh, bfx) do {                                            \
    _Pragma("unroll") for (int i = 0; i < 2; ++i) {                           \
      const int row = wn + ((nh) * 2 + i) * 16 + lrow;                        \
      const int sw = (row & 7) << 4;                                          \
      bfx[i][0] = *(const bf16x8*)&Bs[dbuf][row * 128 + (lgk ^ sw)];          \
      bfx[i][1] = *(const bf16x8*)&Bs[dbuf][row * 128 + ((64 + lgk) ^ sw)];   \
    } } while (0)
#define MFMA_Q(mh, nh, bfx) do {                                              \
    __builtin_amdgcn_s_setprio(1);                                            \
    _Pragma("unroll") for (int kk = 0; kk < 2; ++kk)                          \
    _Pragma("unroll") for (int i = 0; i < 4; ++i)                             \
    _Pragma("unroll") for (int n = 0; n < 2; ++n)                             \
      acc[(mh) * 4 + i][(nh) * 2 + n] = __builtin_amdgcn_mfma_f32_16x16x32_bf16(\
          af[i][kk], bfx[n][kk], acc[(mh) * 4 + i][(nh) * 2 + n], 0, 0, 0);   \
    __builtin_amdgcn_s_setprio(0);                                            \
  } while (0)
#define BAR() __builtin_amdgcn_s_barrier()
#define LGKM0() do { asm volatile("s_waitcnt lgkmcnt(0)" ::: "memory");       \
    __builtin_amdgcn_sched_barrier(0); } while (0)
#define VMCNT6() asm volatile("s_waitcnt vmcnt(6)" ::: "memory")
#define VMCNT0() asm volatile("s_waitcnt vmcnt(0)" ::: "memory")

  ISSUE_A(0, 0); ISSUE_B(0, 0); ISSUE_B(0, 1); ISSUE_A(0, 1);
  __syncthreads();
  ISSUE_A(1, 0); ISSUE_B(1, 0); ISSUE_B(1, 1);

  for (int a = 0; a < NT; a += 2) {
    const int d0 = a & 1, d1 = d0 ^ 1;
    const bool g2 = (a + 2) < NT, g3 = (a + 3) < NT;
    // ---- tile a ----
    READ_A(d0, 0); READ_B(d0, 0, bf0);
    ISSUE_A(a + 1, 1);
    BAR(); LGKM0();
    MFMA_Q(0, 0, bf0);
    BAR();
    READ_B(d0, 1, bf1);
    if (g2) ISSUE_A(a + 2, 0);
    BAR(); LGKM0();
    MFMA_Q(0, 1, bf1);
    BAR();
    READ_A(d0, 1);
    if (g2) ISSUE_B(a + 2, 0);
    BAR(); LGKM0();
    MFMA_Q(1, 0, bf0);
    BAR();
    if (g2) { ISSUE_B(a + 2, 1); VMCNT6(); } else { VMCNT0(); }
    BAR();
    MFMA_Q(1, 1, bf1);
    BAR();
    // ---- tile a+1 ----
    READ_A(d1, 0); READ_B(d1, 0, bf0);
    if (g2) ISSUE_A(a + 2, 1);
    BAR(); LGKM0();
    MFMA_Q(0, 0, bf0);
    BAR();
    READ_B(d1, 1, bf1);
    if (g3) ISSUE_A(a + 3, 0);
    BAR(); LGKM0();
    MFMA_Q(0, 1, bf1);
    BAR();
    READ_A(d1, 1);
    if (g3) ISSUE_B(a + 3, 0);
    BAR(); LGKM0();
    MFMA_Q(1, 0, bf0);
    BAR();
    if (g3) { ISSUE_B(a + 3, 1); VMCNT6(); } else { VMCNT0(); }
    BAR();
    MFMA_Q(1, 1, bf1);
    BAR();
  }
#undef ISSUE_A
#undef ISSUE_B
#undef READ_A
#undef READ_B
#undef MFMA_Q
#undef BAR
#undef LGKM0
#undef VMCNT6
#undef VMCNT0

#pragma unroll
  for (int mi = 0; mi < 8; ++mi) {
    const int row = m0 + wm + mi * 16 + ((lane >> 4) << 2);
#pragma unroll
    for (int ni = 0; ni < 4; ++ni) {
      const int col = n0 + wn + ni * 16 + lrow;
      const float bvv = bias[col];
#pragma unroll
      for (int r = 0; r < 4; ++r) {
        float v = acc[mi][ni][r] + bvv;
        if (MODE == 1) v = fmaxf(v, 0.0f);
        const int rr = row + r;
        if constexpr (MODE == 2) {
          const int part = col >> 10, cc = col & 1023, h = cc >> 6, e = cc & 63;
          if (part == 0) v *= 0.18033688011112042f;
          unsigned short* dst = part == 0 ? qb : (part == 1 ? kb : vb);
          dst[(((size_t)((rr >> 11) * 16 + h)) * 2048 + (rr & 2047)) * 64 + e] = f2bf(v);
        } else {
          out[(size_t)rr * N + col] = f2bf(v);
        }
      }
    }
  }
}

// ---------- bf16 GEMM 128x128: out[M][N] = A[M][K]*Bt[N][K]^T + bias ----------
// MODE 0: bf16 out, 1: +relu, 2: split q/k/v (+q pre-scale 0.125*log2e)
template <int MODE>
__global__ __launch_bounds__(256, 2) void gemm_bt(
    const unsigned short* __restrict__ A, const unsigned short* __restrict__ Bt,
    const float* __restrict__ bias, unsigned short* __restrict__ out,
    unsigned short* __restrict__ qb, unsigned short* __restrict__ kb,
    unsigned short* __restrict__ vb, int M, int N, int K) {
  __shared__ __align__(16) char As[16384];
  __shared__ __align__(16) char Bs[16384];
  const int tid = threadIdx.x;
  const int wave = tid >> 6, lane = tid & 63;
  const int lrow = lane & 15;
  const int kof = (lane >> 4) * 16;
  const int m0 = blockIdx.y * 128, n0 = blockIdx.x * 128;
  const int wm = (wave >> 1) * 64, wn = (wave & 1) * 64;
  const int chunkrow = lane >> 3;
  const int colb0 = (lane & 7) * 16;

  f32x4 acc[4][4] = {};

  for (int k0 = 0; k0 < K; k0 += 64) {
#pragma unroll
    for (int c = 0; c < 4; ++c) {
      const int chunk = wave * 4 + c;
      const int rowA = chunk * 8 + chunkrow;
      const int srcb = colb0 ^ ((rowA & 7) << 4);
      const char* ga = (const char*)A + ((size_t)(m0 + rowA) * K + k0) * 2 + srcb;
      const char* gb = (const char*)Bt + ((size_t)(n0 + rowA) * K + k0) * 2 + srcb;
      gload_lds16(ga, As + chunk * 1024);
      gload_lds16(gb, Bs + chunk * 1024);
    }
    __syncthreads();
#pragma unroll
    for (int kk = 0; kk < 2; ++kk) {
      bf16x8 af[4], bv4[4];
#pragma unroll
      for (int i = 0; i < 4; ++i) {
        const int ra = wm + i * 16 + lrow;
        af[i] = *(const bf16x8*)(As + ra * 128 + ((kk * 64 + kof) ^ ((ra & 7) << 4)));
        const int rb = wn + i * 16 + lrow;
        bv4[i] = *(const bf16x8*)(Bs + rb * 128 + ((kk * 64 + kof) ^ ((rb & 7) << 4)));
      }
#pragma unroll
      for (int mi = 0; mi < 4; ++mi)
#pragma unroll
        for (int ni = 0; ni < 4; ++ni)
          acc[mi][ni] = __builtin_amdgcn_mfma_f32_16x16x32_bf16(af[mi], bv4[ni], acc[mi][ni], 0, 0, 0);
    }
    __syncthreads();
  }

#pragma unroll
  for (int mi = 0; mi < 4; ++mi) {
    const int row = m0 + wm + mi * 16 + ((lane >> 4) << 2);
#pragma unroll
    for (int ni = 0; ni < 4; ++ni) {
      const int col = n0 + wn + ni * 16 + lrow;
      const float bvv = bias[col];
#pragma unroll
      for (int r = 0; r < 4; ++r) {
        float v = acc[mi][ni][r] + bvv;
        if (MODE == 1) v = fmaxf(v, 0.0f);
        const int rr = row + r;
        if constexpr (MODE == 2) {
          const int part = col >> 10, cc = col & 1023, h = cc >> 6, e = cc & 63;
          if (part == 0) v *= 0.18033688011112042f;  // 0.125*log2(e)
          unsigned short* dst = part == 0 ? qb : (part == 1 ? kb : vb);
          dst[(((size_t)((rr >> 11) * 16 + h)) * 2048 + (rr & 2047)) * 64 + e] = f2bf(v);
        } else {
          out[(size_t)rr * N + col] = f2bf(v);
        }
      }
    }
  }
}

// ---------- flash attention v4: raw exp, MFMA denominator, b128 V-frags ----------
__global__ __launch_bounds__(256, 4) void attn_kernel(
    const unsigned short* __restrict__ q_buf, const unsigned short* __restrict__ k_buf,
    const unsigned short* __restrict__ vt_buf, unsigned short* __restrict__ ctx) {
  __shared__ __align__(16) char Ks[2][8192];   // [64 kv][64 d] bf16, swizzled
  __shared__ __align__(16) char Vs[2][8192];   // [64 d][64 kv(perm)] bf16, swizzled
  const int tid = threadIdx.x, wave = tid >> 6, lane = tid & 63;
  const int wg = (blockIdx.x & 7) * 128 + (blockIdx.x >> 3);
  const int bh = wg >> 4;
  const int q0 = (wg & 15) * 128;
  const int l31 = lane & 31, hi = lane >> 5;

  bf16x8 qf[4];
#pragma unroll
  for (int kk = 0; kk < 4; ++kk)
    qf[kk] = *(const bf16x8*)(q_buf +
        ((size_t)bh * 2048 + q0 + wave * 32 + l31) * 64 + kk * 16 + hi * 8);

  f32x16 acc_o[2] = {};
  f32x16 accd = {};
  bf16x8 ones;
#pragma unroll
  for (int j = 0; j < 8; ++j) ones[j] = (__bf16)1.0f;

  auto stage = [&](int t, int buf) {
#pragma unroll
    for (int i = 0; i < 2; ++i) {
      const int c = i * 256 + wave * 64 + lane;
      const int row = c >> 3;
      const int col = ((c & 7) * 16) ^ ((row & 7) << 4);
      gload_lds16((const char*)k_buf + ((size_t)(bh * 2048 + t * 64 + row)) * 128 + col,
                  &Ks[buf][(i * 256 + wave * 64) * 16]);
      gload_lds16((const char*)vt_buf + ((size_t)(bh * 64 + row)) * 4096 + t * 128 + col,
                  &Vs[buf][(i * 256 + wave * 64) * 16]);
    }
  };

  stage(0, 0);
  for (int t = 0; t < 32; ++t) {
    const int cur = t & 1;
    __syncthreads();
    stage(t < 31 ? t + 1 : 31, cur ^ 1);

    // S^T = K * Q^T (M=64 kv via 2 m-tiles, N=32 q, K=64 d)
    f32x16 sacc[2] = {};
#pragma unroll
    for (int kk = 0; kk < 4; ++kk) {
      bf16x8 kf[2];
#pragma unroll
      for (int mt = 0; mt < 2; ++mt) {
        const int row = mt * 32 + l31;
        kf[mt] = *(const bf16x8*)&Ks[cur][row * 128 + ((kk * 32 + hi * 16) ^ ((row & 7) << 4))];
      }
      __builtin_amdgcn_s_setprio(1);
#pragma unroll
      for (int mt = 0; mt < 2; ++mt)
        sacc[mt] = __builtin_amdgcn_mfma_f32_32x32x16_bf16(kf[mt], qf[kk], sacc[mt], 0, 0, 0);
      __builtin_amdgcn_s_setprio(0);
    }

    // p = 2^s in place (scale folded into Q); no guard (bounded inputs)
#pragma unroll
    for (int mt = 0; mt < 2; ++mt)
#pragma unroll
      for (int r = 0; r < 16; ++r)
        sacc[mt][r] = fexp2(sacc[mt][r]);

    // O^T += V^T * P^T ; den += ones * P^T (on MFMA pipe).
    // Sub-MFMA g: kv = 32(g>>1)+16(g&1)+8(j>>2)+4hi+(j&3); Vt pre-permuted so
    // V-frag = one b128 at phys col 16g+8hi.
#pragma unroll
    for (int g = 0; g < 4; ++g) {
      const int m = g >> 1, c = g & 1;
      unsigned w0 = pkbf(sacc[m][8 * c + 0], sacc[m][8 * c + 1]);
      unsigned w1 = pkbf(sacc[m][8 * c + 2], sacc[m][8 * c + 3]);
      unsigned w2 = pkbf(sacc[m][8 * c + 4], sacc[m][8 * c + 5]);
      unsigned w3 = pkbf(sacc[m][8 * c + 6], sacc[m][8 * c + 7]);
      u32x4 bw = {w0, w1, w2, w3};
      bf16x8 pb = __builtin_bit_cast(bf16x8, bw);
      bf16x8 vf[2];
#pragma unroll
      for (int mtd = 0; mtd < 2; ++mtd) {
        const int row = mtd * 32 + l31;
        const int sw = (row & 7) << 4;
        vf[mtd] = *(const bf16x8*)&Vs[cur][row * 128 + ((g * 32 + hi * 16) ^ sw)];
      }
      __builtin_amdgcn_s_setprio(1);
      accd = __builtin_amdgcn_mfma_f32_32x32x16_bf16(ones, pb, accd, 0, 0, 0);
#pragma unroll
      for (int mtd = 0; mtd < 2; ++mtd)
        acc_o[mtd] = __builtin_amdgcn_mfma_f32_32x32x16_bf16(vf[mtd], pb, acc_o[mtd], 0, 0, 0);
      __builtin_amdgcn_s_setprio(0);
    }
  }

  // accd rows are all identical (ones A); K-dim spanned both lane halves ->
  // accd[0] = full denominator for q = l31, no cross-lane needed.
  const float inv = 1.0f / accd[0];
  const int b = bh >> 4, h = bh & 15;
  const size_t orow = ((size_t)(b * 2048 + q0 + wave * 32 + l31)) * 1024 + h * 64;
#pragma unroll
  for (int mtd = 0; mtd < 2; ++mtd)
#pragma unroll
    for (int gq = 0; gq < 4; ++gq) {
      u16x4 o;
#pragma unroll
      for (int e = 0; e < 4; ++e) o[e] = f2bf(acc_o[mtd][gq * 4 + e] * inv);
      *(u16x4*)(ctx + orow + mtd * 32 + gq * 8 + hi * 4) = o;
    }
}

// ---------- residual + layernorm (block per row, D=1024) ----------
template <bool RES_BF, bool OUT_F32>
__global__ __launch_bounds__(256) void ln_kernel(
    const unsigned short* __restrict__ xin, const void* __restrict__ res,
    const float* __restrict__ g, const float* __restrict__ b, void* __restrict__ out) {
  const int row = blockIdx.x, tid = threadIdx.x;
  const size_t base = (size_t)row * 1024 + tid * 4;
  float x[4];
  u16x4 xv = *(const u16x4*)(xin + base);
  if constexpr (RES_BF) {
    u16x4 rv = *(const u16x4*)((const unsigned short*)res + base);
#pragma unroll
    for (int j = 0; j < 4; ++j) x[j] = bf2f(xv[j]) + bf2f(rv[j]);
  } else {
    f32x4 rv = *(const f32x4*)((const float*)res + base);
#pragma unroll
    for (int j = 0; j < 4; ++j) x[j] = bf2f(xv[j]) + rv[j];
  }
  float s1 = 0.f, s2 = 0.f;
#pragma unroll
  for (int j = 0; j < 4; ++j) { s1 += x[j]; s2 += x[j] * x[j]; }
#pragma unroll
  for (int off = 32; off > 0; off >>= 1) {
    s1 += __shfl_down(s1, off);
    s2 += __shfl_down(s2, off);
  }
  __shared__ float red[8];
  const int wv = tid >> 6, ln = tid & 63;
  if (ln == 0) { red[wv] = s1; red[4 + wv] = s2; }
  __syncthreads();
  s1 = red[0] + red[1] + red[2] + red[3];
  s2 = red[4] + red[5] + red[6] + red[7];
  const float mu = s1 * (1.0f / 1024.0f);
  const float rs = rsqrtf(s2 * (1.0f / 1024.0f) - mu * mu + 1e-5f);
#pragma unroll
  for (int j = 0; j < 4; ++j) {
    const float y = (x[j] - mu) * rs * g[tid * 4 + j] + b[tid * 4 + j];
    if constexpr (OUT_F32) ((float*)out)[base + j] = y;
    else ((unsigned short*)out)[base + j] = f2bf(y);
  }
}

// ---------- workspace layout (bytes) ----------
static const size_t OFF_SBF  = 0;            // 16 MiB (bf16 src) ; reused as h1 later
static const size_t OFF_Q    = 16777216;
static const size_t OFF_K    = 33554432;
static const size_t OFF_V    = 50331648;
static const size_t OFF_VT   = 67108864;
static const size_t OFF_WQKV = 83886080;
static const size_t OFF_BQKV = 90177536;
static const size_t OFF_WO   = 90189824;
static const size_t OFF_W1   = 92286976;
static const size_t OFF_W2   = 100675584;
static const size_t OFF_CTX  = 109064192;
static const size_t OFF_AO   = 125841408;
static const size_t OFF_X1   = 142618624;
static const size_t OFF_FFN  = 159395840;
// total = 176173056 bytes

extern "C" void kernel_launch(void* const* d_in, const int* in_sizes, int n_in,
                              void* d_out, int out_size, void* d_ws, size_t ws_size,
                              hipStream_t stream) {
  const float* src = (const float*)d_in[0];
  const float* Wq  = (const float*)d_in[1];
  const float* bq  = (const float*)d_in[2];
  const float* Wk  = (const float*)d_in[3];
  const float* bk  = (const float*)d_in[4];
  const float* Wv  = (const float*)d_in[5];
  const float* bv  = (const float*)d_in[6];
  const float* Wo  = (const float*)d_in[7];
  const float* bo  = (const float*)d_in[8];
  const float* g1  = (const float*)d_in[9];
  const float* be1 = (const float*)d_in[10];
  const float* W1  = (const float*)d_in[11];
  const float* b1  = (const float*)d_in[12];
  const float* W2  = (const float*)d_in[13];
  const float* b2  = (const float*)d_in[14];
  const float* g2  = (const float*)d_in[15];
  const float* be2 = (const float*)d_in[16];

  char* ws = (char*)d_ws;
  unsigned short* sbf  = (unsigned short*)(ws + OFF_SBF);
  unsigned short* h1   = (unsigned short*)(ws + OFF_SBF);  // alias (sbf/q/k/v dead by then)
  unsigned short* qb   = (unsigned short*)(ws + OFF_Q);
  unsigned short* kb   = (unsigned short*)(ws + OFF_K);
  unsigned short* vb   = (unsigned short*)(ws + OFF_V);
  unsigned short* vtb  = (unsigned short*)(ws + OFF_VT);
  unsigned short* wqkv = (unsigned short*)(ws + OFF_WQKV);
  float*          bqkv = (float*)(ws + OFF_BQKV);
  unsigned short* wot  = (unsigned short*)(ws + OFF_WO);
  unsigned short* w1t  = (unsigned short*)(ws + OFF_W1);
  unsigned short* w2t  = (unsigned short*)(ws + OFF_W2);
  unsigned short* ctx  = (unsigned short*)(ws + OFF_CTX);
  unsigned short* ao   = (unsigned short*)(ws + OFF_AO);
  unsigned short* x1   = (unsigned short*)(ws + OFF_X1);
  unsigned short* ffn  = (unsigned short*)(ws + OFF_FFN);
  float* outp = (float*)d_out;

  // 1) casts / packing
  cvt_f32_bf16<<<dim3(8192), dim3(256), 0, stream>>>(src, sbf, 8388608);
  pack_qkv_w<<<dim3(16, 1, 48), dim3(256), 0, stream>>>(Wq, Wk, Wv, wqkv);
  pack_bias<<<dim3(12), dim3(256), 0, stream>>>(bq, bk, bv, bqkv);
  transpose_cvt<<<dim3(16, 16), dim3(256), 0, stream>>>(Wo, wot, 1024, 1024);
  transpose_cvt<<<dim3(16, 64), dim3(256), 0, stream>>>(W1, w1t, 1024, 4096);
  transpose_cvt<<<dim3(64, 16), dim3(256), 0, stream>>>(W2, w2t, 4096, 1024);

  // 2) QKV projection (128^2): [8192,1024] x [3072,1024]^T
  gemm_bt<2><<<dim3(24, 64), dim3(256), 0, stream>>>(sbf, wqkv, bqkv, nullptr, qb, kb, vb,
                                                     8192, 3072, 1024);
  // 3) V transpose (kv-permuted) for PV
  vtrans<<<dim3(32, 64), dim3(256), 0, stream>>>(vb, vtb);
  // 4) attention
  attn_kernel<<<dim3(1024), dim3(256), 0, stream>>>(qb, kb, vtb, ctx);
  // 5) output projection (128^2)
  gemm_bt<0><<<dim3(8, 64), dim3(256), 0, stream>>>(ctx, wot, bo, ao, nullptr, nullptr, nullptr,
                                                    8192, 1024, 1024);
  // 6) LN1 (attn_out + src)
  ln_kernel<false, false><<<dim3(8192), dim3(256), 0, stream>>>(ao, src, g1, be1, x1);
  // 7) FFN (FFN1 on 8-phase v2 — H8 testbed; FFN2 on 128^2)
  gemm8<1><<<dim3(512), dim3(512), 0, stream>>>(x1, w1t, b1, h1, nullptr, nullptr, nullptr,
                                                8192, 4096, 1024, 16);
  gemm_bt<0><<<dim3(8, 64), dim3(256), 0, stream>>>(h1, w2t, b2, ffn, nullptr, nullptr, nullptr,
                                                    8192, 1024, 4096);
  // 8) LN2 (ffn + x1) -> f32 output
  ln_kernel<true, true><<<dim3(8192), dim3(256), 0, stream>>>(ffn, x1, g2, be2, outp);

  (void)in_sizes; (void)n_in; (void)out_size; (void)ws_size;
}

// Round 7
// 370.181 us; speedup vs baseline: 1.0967x; 1.0065x over previous
//
#include <hip/hip_runtime.h>
#include <stdint.h>

#define DEV __device__ __forceinline__

typedef float f32x4 __attribute__((ext_vector_type(4)));
typedef float f32x16 __attribute__((ext_vector_type(16)));
typedef __bf16 bf16x8 __attribute__((ext_vector_type(8)));
typedef __bf16 bf16x4 __attribute__((ext_vector_type(4)));
typedef unsigned short u16x4 __attribute__((ext_vector_type(4)));
typedef unsigned short u16x8 __attribute__((ext_vector_type(8)));
typedef unsigned u32x4 __attribute__((ext_vector_type(4)));

// ---------- helpers ----------
DEV unsigned short f2bf(float f) {
  unsigned u = __builtin_bit_cast(unsigned, f);
  u += 0x7fffu + ((u >> 16) & 1u);   // RNE
  return (unsigned short)(u >> 16);
}
DEV float bf2f(unsigned short h) {
  unsigned u = ((unsigned)h) << 16;
  return __builtin_bit_cast(float, u);
}
DEV unsigned pkbf(float lo, float hi) {  // D.lo=bf16(S0), D.hi=bf16(S1)
  unsigned r;
  asm("v_cvt_pk_bf16_f32 %0, %1, %2" : "=v"(r) : "v"(lo), "v"(hi));
  return r;
}
DEV float fexp2(float x) {  // raw v_exp_f32: inputs bounded, no denormal guard needed
  float r;
  asm("v_exp_f32 %0, %1" : "=v"(r) : "v"(x));
  return r;
}
DEV void gload_lds16(const void* g, void* l) {
  __builtin_amdgcn_global_load_lds((const __attribute__((address_space(1))) void*)g,
                                   (__attribute__((address_space(3))) void*)l, 16, 0, 0);
}

// ---------- elementwise f32 -> bf16 ----------
__global__ void cvt_f32_bf16(const float* __restrict__ in, unsigned short* __restrict__ out, int n) {
  int i = (blockIdx.x * 256 + threadIdx.x) * 4;
  if (i >= n) return;
  f32x4 v = *(const f32x4*)(in + i);
  u16x4 o;
  o[0] = f2bf(v[0]); o[1] = f2bf(v[1]); o[2] = f2bf(v[2]); o[3] = f2bf(v[3]);
  *(u16x4*)(out + i) = o;
}

// ---------- generic f32 [R][C] -> bf16 [C][R] transpose (64x64 tiles) ----------
__global__ void transpose_cvt(const float* __restrict__ src, unsigned short* __restrict__ dst,
                              int R, int C) {
  __shared__ __align__(16) float t[64][65];
  const int tid = threadIdx.x;
  const int r0 = blockIdx.x * 64, c0 = blockIdx.y * 64;
  const int rr = tid >> 2, q = tid & 3;
  const float* s = src + (size_t)(r0 + rr) * C + c0 + q * 16;
#pragma unroll
  for (int j = 0; j < 4; ++j) {
    f32x4 v = *(const f32x4*)(s + j * 4);
    t[rr][q * 16 + j * 4 + 0] = v[0];
    t[rr][q * 16 + j * 4 + 1] = v[1];
    t[rr][q * 16 + j * 4 + 2] = v[2];
    t[rr][q * 16 + j * 4 + 3] = v[3];
  }
  __syncthreads();
  const int cc = tid >> 2, qq = tid & 3;
  unsigned short* o = dst + (size_t)(c0 + cc) * R + r0 + qq * 16;
  u16x8 a, b;
#pragma unroll
  for (int j = 0; j < 8; ++j) {
    a[j] = f2bf(t[qq * 16 + j][cc]);
    b[j] = f2bf(t[qq * 16 + 8 + j][cc]);
  }
  *(u16x8*)o = a;
  *(u16x8*)(o + 8) = b;
}

// ---------- pack per-head Wq/Wk/Wv [16][1024][64] -> Bt bf16 [3072][1024] ----------
__global__ void pack_qkv_w(const float* __restrict__ Wq, const float* __restrict__ Wk,
                           const float* __restrict__ Wv, unsigned short* __restrict__ dst) {
  __shared__ __align__(16) float t[64][65];
  const int tid = threadIdx.x;
  const int z = blockIdx.z, part = z >> 4, h = z & 15;
  const float* src = (part == 0 ? Wq : (part == 1 ? Wk : Wv)) + (size_t)h * 65536;
  const int r0 = blockIdx.x * 64;  // d tile
  const int rr = tid >> 2, q = tid & 3;
  const float* s = src + (size_t)(r0 + rr) * 64 + q * 16;
#pragma unroll
  for (int j = 0; j < 4; ++j) {
    f32x4 v = *(const f32x4*)(s + j * 4);
    t[rr][q * 16 + j * 4 + 0] = v[0];
    t[rr][q * 16 + j * 4 + 1] = v[1];
    t[rr][q * 16 + j * 4 + 2] = v[2];
    t[rr][q * 16 + j * 4 + 3] = v[3];
  }
  __syncthreads();
  const int cc = tid >> 2, qq = tid & 3;  // cc = e
  unsigned short* o = dst + ((size_t)(part * 1024 + h * 64 + cc)) * 1024 + r0 + qq * 16;
  u16x8 a, b;
#pragma unroll
  for (int j = 0; j < 8; ++j) {
    a[j] = f2bf(t[qq * 16 + j][cc]);
    b[j] = f2bf(t[qq * 16 + 8 + j][cc]);
  }
  *(u16x8*)o = a;
  *(u16x8*)(o + 8) = b;
}

__global__ void pack_bias(const float* __restrict__ bq, const float* __restrict__ bk,
                          const float* __restrict__ bv, float* __restrict__ o) {
  int i = blockIdx.x * 256 + threadIdx.x;  // 0..3071
  o[i] = i < 1024 ? bq[i] : (i < 2048 ? bk[i - 1024] : bv[i - 2048]);
}

// ---------- transpose V [bh][2048][64] -> Vt [bh][64][2048] (bf16) ----------
// kv columns PERMUTED within each 16-group (swap bits 2<->3) so attn's PV
// A-fragment (slots psi(g,hi,j)) is one contiguous b128 read.
__global__ void vtrans(const unsigned short* __restrict__ v, unsigned short* __restrict__ vt) {
  __shared__ __align__(16) unsigned short t[64][72];
  const int tid = threadIdx.x;
  const int bh = blockIdx.y, s0 = blockIdx.x * 64;
  const int r = tid >> 2, q = (tid & 3) * 16;
  const unsigned short* g = v + ((size_t)bh * 2048 + s0 + r) * 64 + q;
  *(u16x8*)&t[r][q] = *(const u16x8*)g;
  *(u16x8*)&t[r][q + 8] = *(const u16x8*)(g + 8);
  __syncthreads();
  const int d = tid >> 2, qq = (tid & 3) * 16;
  unsigned short* o = vt + ((size_t)bh * 64 + d) * 2048 + s0 + qq;
  u16x8 a, b;
#pragma unroll
  for (int j = 0; j < 8; ++j) {
    const int sa = (j & 3) | ((j & 4) << 1);   // 0,1,2,3,8,9,10,11
    a[j] = t[qq + sa][d];
    b[j] = t[qq + sa + 4][d];                  // 4,5,6,7,12,13,14,15
  }
  *(u16x8*)o = a;
  *(u16x8*)(o + 8) = b;
}

// ================= 256x256 8-phase GEMM (T2+T3+T4+T5) =================
// v3 (H9 fix): NO manual lgkmcnt(0)/sched_barrier — ds_reads are C++ loads,
// so the compiler emits fine-grained per-MFMA lgkmcnt(N) waits and overlaps
// LDS service with the MFMA stream (m141 lesson: order-pinning regresses).
// Safety invariant preserved: every phase's ds_reads are consumed by that
// phase's MFMAs (compiler dep waits) -> complete before the closing barrier
// -> before any gload overwrites that region. vmcnt asm keeps "memory"
// clobber so later LDS reads can't hoist above buffer-readiness waits.
template <int MODE>
__global__ __launch_bounds__(512, 2) void gemm8(
    const unsigned short* __restrict__ A, const unsigned short* __restrict__ Bt,
    const float* __restrict__ bias, unsigned short* __restrict__ out,
    unsigned short* __restrict__ qb, unsigned short* __restrict__ kb,
    unsigned short* __restrict__ vb, int M, int N, int K, int NBN) {
  __shared__ __align__(16) char As[2][32768];
  __shared__ __align__(16) char Bs[2][32768];
  const int tid = threadIdx.x, wave = tid >> 6, lane = tid & 63;
  const int lrow = lane & 15, lgk = (lane >> 4) * 16;
  const int cr = lane >> 3;
  const int csw = ((lane & 7) * 16) ^ (cr << 4);
  const int nwg = gridDim.x, bid = blockIdx.x;
  const int wg = (bid & 7) * (nwg >> 3) + (bid >> 3);   // bijective (nwg%8==0)
  const int bm = wg / NBN, bn = wg % NBN;
  const int m0 = bm * 256, n0 = bn * 256;
  const int wm = (wave >> 2) * 128, wn = (wave & 3) * 64;
  const char* Ab = (const char*)A;
  const char* Bb = (const char*)Bt;
  const int NT = K >> 6;

  f32x4 acc[8][4] = {};
  bf16x8 af[4][2];
  bf16x8 bf0[2][2], bf1[2][2];

#define ISSUE_A(kt, half) do {                                                \
    _Pragma("unroll") for (int rep = 0; rep < 2; ++rep) {                     \
      const int j = wave * 2 + rep;                                           \
      const int row0 = j * 8 + ((j >= 8) ? 64 : 0) + (half) * 64;             \
      gload_lds16(Ab + (((size_t)(m0 + row0 + cr) * K + (kt) * 64) << 1) + csw,\
                  &As[(kt) & 1][row0 * 128]);                                 \
    } } while (0)
#define ISSUE_B(kt, half) do {                                                \
    _Pragma("unroll") for (int rep = 0; rep < 2; ++rep) {                     \
      const int j = wave * 2 + rep;                                           \
      const int row0 = (j >> 2) * 64 + (j & 3) * 8 + (half) * 32;             \
      gload_lds16(Bb + (((size_t)(n0 + row0 + cr) * K + (kt) * 64) << 1) + csw,\
                  &Bs[(kt) & 1][row0 * 128]);                                 \
    } } while (0)
#define READ_A(dbuf, mh) do {                                                 \
    _Pragma("unroll") for (int i = 0; i < 4; ++i) {                           \
      const int row = wm + ((mh) * 4 + i) * 16 + lrow;                        \
      const int sw = (row & 7) << 4;                                          \
      af[i][0] = *(const bf16x8*)&As[dbuf][row * 128 + (lgk ^ sw)];           \
      af[i][1] = *(const bf16x8*)&As[dbuf][row * 128 + ((64 + lgk) ^ sw)];    \
    } } while (0)
#define READ_B(dbuf, nh, bfx) do {                                            \
    _Pragma("unroll") for (int i = 0; i < 2; ++i) {                           \
      const int row = wn + ((nh) * 2 + i) * 16 + lrow;                        \
      const int sw = (row & 7) << 4;                                          \
      bfx[i][0] = *(const bf16x8*)&Bs[dbuf][row * 128 + (lgk ^ sw)];          \
      bfx[i][1] = *(const bf16x8*)&Bs[dbuf][row * 128 + ((64 + lgk) ^ sw)];   \
    } } while (0)
#define MFMA_Q(mh, nh, bfx) do {                                              \
    __builtin_amdgcn_s_setprio(1);                                            \
    _Pragma("unroll") for (int kk = 0; kk < 2; ++kk)                          \
    _Pragma("unroll") for (int i = 0; i < 4; ++i)                             \
    _Pragma("unroll") for (int n = 0; n < 2; ++n)                             \
      acc[(mh) * 4 + i][(nh) * 2 + n] = __builtin_amdgcn_mfma_f32_16x16x32_bf16(\
          af[i][kk], bfx[n][kk], acc[(mh) * 4 + i][(nh) * 2 + n], 0, 0, 0);   \
    __builtin_amdgcn_s_setprio(0);                                            \
  } while (0)
#define BAR() __builtin_amdgcn_s_barrier()
#define VMCNT6() asm volatile("s_waitcnt vmcnt(6)" ::: "memory")
#define VMCNT0() asm volatile("s_waitcnt vmcnt(0)" ::: "memory")

  ISSUE_A(0, 0); ISSUE_B(0, 0); ISSUE_B(0, 1); ISSUE_A(0, 1);
  __syncthreads();
  ISSUE_A(1, 0); ISSUE_B(1, 0); ISSUE_B(1, 1);

  for (int a = 0; a < NT; a += 2) {
    const int d0 = a & 1, d1 = d0 ^ 1;
    const bool g2 = (a + 2) < NT, g3 = (a + 3) < NT;
    // ---- tile a ----
    READ_A(d0, 0); READ_B(d0, 0, bf0);
    ISSUE_A(a + 1, 1);
    BAR();
    MFMA_Q(0, 0, bf0);
    BAR();
    READ_B(d0, 1, bf1);
    if (g2) ISSUE_A(a + 2, 0);
    BAR();
    MFMA_Q(0, 1, bf1);
    BAR();
    READ_A(d0, 1);
    if (g2) ISSUE_B(a + 2, 0);
    BAR();
    MFMA_Q(1, 0, bf0);
    BAR();
    if (g2) { ISSUE_B(a + 2, 1); VMCNT6(); } else { VMCNT0(); }
    BAR();
    MFMA_Q(1, 1, bf1);
    BAR();
    // ---- tile a+1 ----
    READ_A(d1, 0); READ_B(d1, 0, bf0);
    if (g2) ISSUE_A(a + 2, 1);
    BAR();
    MFMA_Q(0, 0, bf0);
    BAR();
    READ_B(d1, 1, bf1);
    if (g3) ISSUE_A(a + 3, 0);
    BAR();
    MFMA_Q(0, 1, bf1);
    BAR();
    READ_A(d1, 1);
    if (g3) ISSUE_B(a + 3, 0);
    BAR();
    MFMA_Q(1, 0, bf0);
    BAR();
    if (g3) { ISSUE_B(a + 3, 1); VMCNT6(); } else { VMCNT0(); }
    BAR();
    MFMA_Q(1, 1, bf1);
    BAR();
  }
#undef ISSUE_A
#undef ISSUE_B
#undef READ_A
#undef READ_B
#undef MFMA_Q
#undef BAR
#undef VMCNT6
#undef VMCNT0

#pragma unroll
  for (int mi = 0; mi < 8; ++mi) {
    const int row = m0 + wm + mi * 16 + ((lane >> 4) << 2);
#pragma unroll
    for (int ni = 0; ni < 4; ++ni) {
      const int col = n0 + wn + ni * 16 + lrow;
      const float bvv = bias[col];
#pragma unroll
      for (int r = 0; r < 4; ++r) {
        float v = acc[mi][ni][r] + bvv;
        if (MODE == 1) v = fmaxf(v, 0.0f);
        const int rr = row + r;
        if constexpr (MODE == 2) {
          const int part = col >> 10, cc = col & 1023, h = cc >> 6, e = cc & 63;
          if (part == 0) v *= 0.18033688011112042f;
          unsigned short* dst = part == 0 ? qb : (part == 1 ? kb : vb);
          dst[(((size_t)((rr >> 11) * 16 + h)) * 2048 + (rr & 2047)) * 64 + e] = f2bf(v);
        } else {
          out[(size_t)rr * N + col] = f2bf(v);
        }
      }
    }
  }
}

// ---------- bf16 GEMM 128x128: out[M][N] = A[M][K]*Bt[N][K]^T + bias ----------
// MODE 0: bf16 out, 1: +relu, 2: split q/k/v (+q pre-scale 0.125*log2e)
template <int MODE>
__global__ __launch_bounds__(256, 2) void gemm_bt(
    const unsigned short* __restrict__ A, const unsigned short* __restrict__ Bt,
    const float* __restrict__ bias, unsigned short* __restrict__ out,
    unsigned short* __restrict__ qb, unsigned short* __restrict__ kb,
    unsigned short* __restrict__ vb, int M, int N, int K) {
  __shared__ __align__(16) char As[16384];
  __shared__ __align__(16) char Bs[16384];
  const int tid = threadIdx.x;
  const int wave = tid >> 6, lane = tid & 63;
  const int lrow = lane & 15;
  const int kof = (lane >> 4) * 16;
  const int m0 = blockIdx.y * 128, n0 = blockIdx.x * 128;
  const int wm = (wave >> 1) * 64, wn = (wave & 1) * 64;
  const int chunkrow = lane >> 3;
  const int colb0 = (lane & 7) * 16;

  f32x4 acc[4][4] = {};

  for (int k0 = 0; k0 < K; k0 += 64) {
#pragma unroll
    for (int c = 0; c < 4; ++c) {
      const int chunk = wave * 4 + c;
      const int rowA = chunk * 8 + chunkrow;
      const int srcb = colb0 ^ ((rowA & 7) << 4);
      const char* ga = (const char*)A + ((size_t)(m0 + rowA) * K + k0) * 2 + srcb;
      const char* gb = (const char*)Bt + ((size_t)(n0 + rowA) * K + k0) * 2 + srcb;
      gload_lds16(ga, As + chunk * 1024);
      gload_lds16(gb, Bs + chunk * 1024);
    }
    __syncthreads();
#pragma unroll
    for (int kk = 0; kk < 2; ++kk) {
      bf16x8 af[4], bv4[4];
#pragma unroll
      for (int i = 0; i < 4; ++i) {
        const int ra = wm + i * 16 + lrow;
        af[i] = *(const bf16x8*)(As + ra * 128 + ((kk * 64 + kof) ^ ((ra & 7) << 4)));
        const int rb = wn + i * 16 + lrow;
        bv4[i] = *(const bf16x8*)(Bs + rb * 128 + ((kk * 64 + kof) ^ ((rb & 7) << 4)));
      }
#pragma unroll
      for (int mi = 0; mi < 4; ++mi)
#pragma unroll
        for (int ni = 0; ni < 4; ++ni)
          acc[mi][ni] = __builtin_amdgcn_mfma_f32_16x16x32_bf16(af[mi], bv4[ni], acc[mi][ni], 0, 0, 0);
    }
    __syncthreads();
  }

#pragma unroll
  for (int mi = 0; mi < 4; ++mi) {
    const int row = m0 + wm + mi * 16 + ((lane >> 4) << 2);
#pragma unroll
    for (int ni = 0; ni < 4; ++ni) {
      const int col = n0 + wn + ni * 16 + lrow;
      const float bvv = bias[col];
#pragma unroll
      for (int r = 0; r < 4; ++r) {
        float v = acc[mi][ni][r] + bvv;
        if (MODE == 1) v = fmaxf(v, 0.0f);
        const int rr = row + r;
        if constexpr (MODE == 2) {
          const int part = col >> 10, cc = col & 1023, h = cc >> 6, e = cc & 63;
          if (part == 0) v *= 0.18033688011112042f;  // 0.125*log2(e)
          unsigned short* dst = part == 0 ? qb : (part == 1 ? kb : vb);
          dst[(((size_t)((rr >> 11) * 16 + h)) * 2048 + (rr & 2047)) * 64 + e] = f2bf(v);
        } else {
          out[(size_t)rr * N + col] = f2bf(v);
        }
      }
    }
  }
}

// ---------- flash attention v4: raw exp, MFMA denominator, b128 V-frags ----------
__global__ __launch_bounds__(256, 4) void attn_kernel(
    const unsigned short* __restrict__ q_buf, const unsigned short* __restrict__ k_buf,
    const unsigned short* __restrict__ vt_buf, unsigned short* __restrict__ ctx) {
  __shared__ __align__(16) char Ks[2][8192];   // [64 kv][64 d] bf16, swizzled
  __shared__ __align__(16) char Vs[2][8192];   // [64 d][64 kv(perm)] bf16, swizzled
  const int tid = threadIdx.x, wave = tid >> 6, lane = tid & 63;
  const int wg = (blockIdx.x & 7) * 128 + (blockIdx.x >> 3);
  const int bh = wg >> 4;
  const int q0 = (wg & 15) * 128;
  const int l31 = lane & 31, hi = lane >> 5;

  bf16x8 qf[4];
#pragma unroll
  for (int kk = 0; kk < 4; ++kk)
    qf[kk] = *(const bf16x8*)(q_buf +
        ((size_t)bh * 2048 + q0 + wave * 32 + l31) * 64 + kk * 16 + hi * 8);

  f32x16 acc_o[2] = {};
  f32x16 accd = {};
  bf16x8 ones;
#pragma unroll
  for (int j = 0; j < 8; ++j) ones[j] = (__bf16)1.0f;

  auto stage = [&](int t, int buf) {
#pragma unroll
    for (int i = 0; i < 2; ++i) {
      const int c = i * 256 + wave * 64 + lane;
      const int row = c >> 3;
      const int col = ((c & 7) * 16) ^ ((row & 7) << 4);
      gload_lds16((const char*)k_buf + ((size_t)(bh * 2048 + t * 64 + row)) * 128 + col,
                  &Ks[buf][(i * 256 + wave * 64) * 16]);
      gload_lds16((const char*)vt_buf + ((size_t)(bh * 64 + row)) * 4096 + t * 128 + col,
                  &Vs[buf][(i * 256 + wave * 64) * 16]);
    }
  };

  stage(0, 0);
  for (int t = 0; t < 32; ++t) {
    const int cur = t & 1;
    __syncthreads();
    stage(t < 31 ? t + 1 : 31, cur ^ 1);

    // S^T = K * Q^T (M=64 kv via 2 m-tiles, N=32 q, K=64 d)
    f32x16 sacc[2] = {};
#pragma unroll
    for (int kk = 0; kk < 4; ++kk) {
      bf16x8 kf[2];
#pragma unroll
      for (int mt = 0; mt < 2; ++mt) {
        const int row = mt * 32 + l31;
        kf[mt] = *(const bf16x8*)&Ks[cur][row * 128 + ((kk * 32 + hi * 16) ^ ((row & 7) << 4))];
      }
      __builtin_amdgcn_s_setprio(1);
#pragma unroll
      for (int mt = 0; mt < 2; ++mt)
        sacc[mt] = __builtin_amdgcn_mfma_f32_32x32x16_bf16(kf[mt], qf[kk], sacc[mt], 0, 0, 0);
      __builtin_amdgcn_s_setprio(0);
    }

    // p = 2^s in place (scale folded into Q); no guard (bounded inputs)
#pragma unroll
    for (int mt = 0; mt < 2; ++mt)
#pragma unroll
      for (int r = 0; r < 16; ++r)
        sacc[mt][r] = fexp2(sacc[mt][r]);

    // O^T += V^T * P^T ; den += ones * P^T (on MFMA pipe).
    // Sub-MFMA g: kv = 32(g>>1)+16(g&1)+8(j>>2)+4hi+(j&3); Vt pre-permuted so
    // V-frag = one b128 at phys col 16g+8hi.
#pragma unroll
    for (int g = 0; g < 4; ++g) {
      const int m = g >> 1, c = g & 1;
      unsigned w0 = pkbf(sacc[m][8 * c + 0], sacc[m][8 * c + 1]);
      unsigned w1 = pkbf(sacc[m][8 * c + 2], sacc[m][8 * c + 3]);
      unsigned w2 = pkbf(sacc[m][8 * c + 4], sacc[m][8 * c + 5]);
      unsigned w3 = pkbf(sacc[m][8 * c + 6], sacc[m][8 * c + 7]);
      u32x4 bw = {w0, w1, w2, w3};
      bf16x8 pb = __builtin_bit_cast(bf16x8, bw);
      bf16x8 vf[2];
#pragma unroll
      for (int mtd = 0; mtd < 2; ++mtd) {
        const int row = mtd * 32 + l31;
        const int sw = (row & 7) << 4;
        vf[mtd] = *(const bf16x8*)&Vs[cur][row * 128 + ((g * 32 + hi * 16) ^ sw)];
      }
      __builtin_amdgcn_s_setprio(1);
      accd = __builtin_amdgcn_mfma_f32_32x32x16_bf16(ones, pb, accd, 0, 0, 0);
#pragma unroll
      for (int mtd = 0; mtd < 2; ++mtd)
        acc_o[mtd] = __builtin_amdgcn_mfma_f32_32x32x16_bf16(vf[mtd], pb, acc_o[mtd], 0, 0, 0);
      __builtin_amdgcn_s_setprio(0);
    }
  }

  // accd rows are all identical (ones A); K-dim spanned both lane halves ->
  // accd[0] = full denominator for q = l31, no cross-lane needed.
  const float inv = 1.0f / accd[0];
  const int b = bh >> 4, h = bh & 15;
  const size_t orow = ((size_t)(b * 2048 + q0 + wave * 32 + l31)) * 1024 + h * 64;
#pragma unroll
  for (int mtd = 0; mtd < 2; ++mtd)
#pragma unroll
    for (int gq = 0; gq < 4; ++gq) {
      u16x4 o;
#pragma unroll
      for (int e = 0; e < 4; ++e) o[e] = f2bf(acc_o[mtd][gq * 4 + e] * inv);
      *(u16x4*)(ctx + orow + mtd * 32 + gq * 8 + hi * 4) = o;
    }
}

// ---------- residual + layernorm (block per row, D=1024) ----------
template <bool RES_BF, bool OUT_F32>
__global__ __launch_bounds__(256) void ln_kernel(
    const unsigned short* __restrict__ xin, const void* __restrict__ res,
    const float* __restrict__ g, const float* __restrict__ b, void* __restrict__ out) {
  const int row = blockIdx.x, tid = threadIdx.x;
  const size_t base = (size_t)row * 1024 + tid * 4;
  float x[4];
  u16x4 xv = *(const u16x4*)(xin + base);
  if constexpr (RES_BF) {
    u16x4 rv = *(const u16x4*)((const unsigned short*)res + base);
#pragma unroll
    for (int j = 0; j < 4; ++j) x[j] = bf2f(xv[j]) + bf2f(rv[j]);
  } else {
    f32x4 rv = *(const f32x4*)((const float*)res + base);
#pragma unroll
    for (int j = 0; j < 4; ++j) x[j] = bf2f(xv[j]) + rv[j];
  }
  float s1 = 0.f, s2 = 0.f;
#pragma unroll
  for (int j = 0; j < 4; ++j) { s1 += x[j]; s2 += x[j] * x[j]; }
#pragma unroll
  for (int off = 32; off > 0; off >>= 1) {
    s1 += __shfl_down(s1, off);
    s2 += __shfl_down(s2, off);
  }
  __shared__ float red[8];
  const int wv = tid >> 6, ln = tid & 63;
  if (ln == 0) { red[wv] = s1; red[4 + wv] = s2; }
  __syncthreads();
  s1 = red[0] + red[1] + red[2] + red[3];
  s2 = red[4] + red[5] + red[6] + red[7];
  const float mu = s1 * (1.0f / 1024.0f);
  const float rs = rsqrtf(s2 * (1.0f / 1024.0f) - mu * mu + 1e-5f);
#pragma unroll
  for (int j = 0; j < 4; ++j) {
    const float y = (x[j] - mu) * rs * g[tid * 4 + j] + b[tid * 4 + j];
    if constexpr (OUT_F32) ((float*)out)[base + j] = y;
    else ((unsigned short*)out)[base + j] = f2bf(y);
  }
}

// ---------- workspace layout (bytes) ----------
static const size_t OFF_SBF  = 0;            // 16 MiB (bf16 src) ; reused as h1 later
static const size_t OFF_Q    = 16777216;
static const size_t OFF_K    = 33554432;
static const size_t OFF_V    = 50331648;
static const size_t OFF_VT   = 67108864;
static const size_t OFF_WQKV = 83886080;
static const size_t OFF_BQKV = 90177536;
static const size_t OFF_WO   = 90189824;
static const size_t OFF_W1   = 92286976;
static const size_t OFF_W2   = 100675584;
static const size_t OFF_CTX  = 109064192;
static const size_t OFF_AO   = 125841408;
static const size_t OFF_X1   = 142618624;
static const size_t OFF_FFN  = 159395840;
// total = 176173056 bytes

extern "C" void kernel_launch(void* const* d_in, const int* in_sizes, int n_in,
                              void* d_out, int out_size, void* d_ws, size_t ws_size,
                              hipStream_t stream) {
  const float* src = (const float*)d_in[0];
  const float* Wq  = (const float*)d_in[1];
  const float* bq  = (const float*)d_in[2];
  const float* Wk  = (const float*)d_in[3];
  const float* bk  = (const float*)d_in[4];
  const float* Wv  = (const float*)d_in[5];
  const float* bv  = (const float*)d_in[6];
  const float* Wo  = (const float*)d_in[7];
  const float* bo  = (const float*)d_in[8];
  const float* g1  = (const float*)d_in[9];
  const float* be1 = (const float*)d_in[10];
  const float* W1  = (const float*)d_in[11];
  const float* b1  = (const float*)d_in[12];
  const float* W2  = (const float*)d_in[13];
  const float* b2  = (const float*)d_in[14];
  const float* g2  = (const float*)d_in[15];
  const float* be2 = (const float*)d_in[16];

  char* ws = (char*)d_ws;
  unsigned short* sbf  = (unsigned short*)(ws + OFF_SBF);
  unsigned short* h1   = (unsigned short*)(ws + OFF_SBF);  // alias (sbf/q/k/v dead by then)
  unsigned short* qb   = (unsigned short*)(ws + OFF_Q);
  unsigned short* kb   = (unsigned short*)(ws + OFF_K);
  unsigned short* vb   = (unsigned short*)(ws + OFF_V);
  unsigned short* vtb  = (unsigned short*)(ws + OFF_VT);
  unsigned short* wqkv = (unsigned short*)(ws + OFF_WQKV);
  float*          bqkv = (float*)(ws + OFF_BQKV);
  unsigned short* wot  = (unsigned short*)(ws + OFF_WO);
  unsigned short* w1t  = (unsigned short*)(ws + OFF_W1);
  unsigned short* w2t  = (unsigned short*)(ws + OFF_W2);
  unsigned short* ctx  = (unsigned short*)(ws + OFF_CTX);
  unsigned short* ao   = (unsigned short*)(ws + OFF_AO);
  unsigned short* x1   = (unsigned short*)(ws + OFF_X1);
  unsigned short* ffn  = (unsigned short*)(ws + OFF_FFN);
  float* outp = (float*)d_out;

  // 1) casts / packing
  cvt_f32_bf16<<<dim3(8192), dim3(256), 0, stream>>>(src, sbf, 8388608);
  pack_qkv_w<<<dim3(16, 1, 48), dim3(256), 0, stream>>>(Wq, Wk, Wv, wqkv);
  pack_bias<<<dim3(12), dim3(256), 0, stream>>>(bq, bk, bv, bqkv);
  transpose_cvt<<<dim3(16, 16), dim3(256), 0, stream>>>(Wo, wot, 1024, 1024);
  transpose_cvt<<<dim3(16, 64), dim3(256), 0, stream>>>(W1, w1t, 1024, 4096);
  transpose_cvt<<<dim3(64, 16), dim3(256), 0, stream>>>(W2, w2t, 4096, 1024);

  // 2) QKV projection (128^2): [8192,1024] x [3072,1024]^T
  gemm_bt<2><<<dim3(24, 64), dim3(256), 0, stream>>>(sbf, wqkv, bqkv, nullptr, qb, kb, vb,
                                                     8192, 3072, 1024);
  // 3) V transpose (kv-permuted) for PV
  vtrans<<<dim3(32, 64), dim3(256), 0, stream>>>(vb, vtb);
  // 4) attention
  attn_kernel<<<dim3(1024), dim3(256), 0, stream>>>(qb, kb, vtb, ctx);
  // 5) output projection (128^2)
  gemm_bt<0><<<dim3(8, 64), dim3(256), 0, stream>>>(ctx, wot, bo, ao, nullptr, nullptr, nullptr,
                                                    8192, 1024, 1024);
  // 6) LN1 (attn_out + src)
  ln_kernel<false, false><<<dim3(8192), dim3(256), 0, stream>>>(ao, src, g1, be1, x1);
  // 7) FFN (FFN1 on 8-phase v3 — H9 testbed; FFN2 on 128^2)
  gemm8<1><<<dim3(512), dim3(512), 0, stream>>>(x1, w1t, b1, h1, nullptr, nullptr, nullptr,
                                                8192, 4096, 1024, 16);
  gemm_bt<0><<<dim3(8, 64), dim3(256), 0, stream>>>(h1, w2t, b2, ffn, nullptr, nullptr, nullptr,
                                                    8192, 1024, 4096);
  // 8) LN2 (ffn + x1) -> f32 output
  ln_kernel<true, true><<<dim3(8192), dim3(256), 0, stream>>>(ffn, x1, g2, be2, outp);

  (void)in_sizes; (void)n_in; (void)out_size; (void)ws_size;
}

// Round 8
// 364.573 us; speedup vs baseline: 1.1135x; 1.0154x over previous
//
#include <hip/hip_runtime.h>
#include <stdint.h>

#define DEV __device__ __forceinline__

typedef float f32x4 __attribute__((ext_vector_type(4)));
typedef float f32x16 __attribute__((ext_vector_type(16)));
typedef __bf16 bf16x8 __attribute__((ext_vector_type(8)));
typedef __bf16 bf16x4 __attribute__((ext_vector_type(4)));
typedef unsigned short u16x4 __attribute__((ext_vector_type(4)));
typedef unsigned short u16x8 __attribute__((ext_vector_type(8)));
typedef unsigned u32x4 __attribute__((ext_vector_type(4)));

// ---------- helpers ----------
DEV unsigned short f2bf(float f) {
  unsigned u = __builtin_bit_cast(unsigned, f);
  u += 0x7fffu + ((u >> 16) & 1u);   // RNE
  return (unsigned short)(u >> 16);
}
DEV float bf2f(unsigned short h) {
  unsigned u = ((unsigned)h) << 16;
  return __builtin_bit_cast(float, u);
}
DEV unsigned pkbf(float lo, float hi) {  // D.lo=bf16(S0), D.hi=bf16(S1)
  unsigned r;
  asm("v_cvt_pk_bf16_f32 %0, %1, %2" : "=v"(r) : "v"(lo), "v"(hi));
  return r;
}
DEV float fexp2(float x) {  // raw v_exp_f32: inputs bounded, no denormal guard needed
  float r;
  asm("v_exp_f32 %0, %1" : "=v"(r) : "v"(x));
  return r;
}
DEV void gload_lds16(const void* g, void* l) {
  __builtin_amdgcn_global_load_lds((const __attribute__((address_space(1))) void*)g,
                                   (__attribute__((address_space(3))) void*)l, 16, 0, 0);
}

// ---------- elementwise f32 -> bf16 ----------
__global__ void cvt_f32_bf16(const float* __restrict__ in, unsigned short* __restrict__ out, int n) {
  int i = (blockIdx.x * 256 + threadIdx.x) * 4;
  if (i >= n) return;
  f32x4 v = *(const f32x4*)(in + i);
  u16x4 o;
  o[0] = f2bf(v[0]); o[1] = f2bf(v[1]); o[2] = f2bf(v[2]); o[3] = f2bf(v[3]);
  *(u16x4*)(out + i) = o;
}

// ---------- generic f32 [R][C] -> bf16 [C][R] transpose (64x64 tiles) ----------
__global__ void transpose_cvt(const float* __restrict__ src, unsigned short* __restrict__ dst,
                              int R, int C) {
  __shared__ __align__(16) float t[64][65];
  const int tid = threadIdx.x;
  const int r0 = blockIdx.x * 64, c0 = blockIdx.y * 64;
  const int rr = tid >> 2, q = tid & 3;
  const float* s = src + (size_t)(r0 + rr) * C + c0 + q * 16;
#pragma unroll
  for (int j = 0; j < 4; ++j) {
    f32x4 v = *(const f32x4*)(s + j * 4);
    t[rr][q * 16 + j * 4 + 0] = v[0];
    t[rr][q * 16 + j * 4 + 1] = v[1];
    t[rr][q * 16 + j * 4 + 2] = v[2];
    t[rr][q * 16 + j * 4 + 3] = v[3];
  }
  __syncthreads();
  const int cc = tid >> 2, qq = tid & 3;
  unsigned short* o = dst + (size_t)(c0 + cc) * R + r0 + qq * 16;
  u16x8 a, b;
#pragma unroll
  for (int j = 0; j < 8; ++j) {
    a[j] = f2bf(t[qq * 16 + j][cc]);
    b[j] = f2bf(t[qq * 16 + 8 + j][cc]);
  }
  *(u16x8*)o = a;
  *(u16x8*)(o + 8) = b;
}

// ---------- pack per-head Wq/Wk/Wv [16][1024][64] -> Bt bf16 [3072][1024] ----------
__global__ void pack_qkv_w(const float* __restrict__ Wq, const float* __restrict__ Wk,
                           const float* __restrict__ Wv, unsigned short* __restrict__ dst) {
  __shared__ __align__(16) float t[64][65];
  const int tid = threadIdx.x;
  const int z = blockIdx.z, part = z >> 4, h = z & 15;
  const float* src = (part == 0 ? Wq : (part == 1 ? Wk : Wv)) + (size_t)h * 65536;
  const int r0 = blockIdx.x * 64;  // d tile
  const int rr = tid >> 2, q = tid & 3;
  const float* s = src + (size_t)(r0 + rr) * 64 + q * 16;
#pragma unroll
  for (int j = 0; j < 4; ++j) {
    f32x4 v = *(const f32x4*)(s + j * 4);
    t[rr][q * 16 + j * 4 + 0] = v[0];
    t[rr][q * 16 + j * 4 + 1] = v[1];
    t[rr][q * 16 + j * 4 + 2] = v[2];
    t[rr][q * 16 + j * 4 + 3] = v[3];
  }
  __syncthreads();
  const int cc = tid >> 2, qq = tid & 3;  // cc = e
  unsigned short* o = dst + ((size_t)(part * 1024 + h * 64 + cc)) * 1024 + r0 + qq * 16;
  u16x8 a, b;
#pragma unroll
  for (int j = 0; j < 8; ++j) {
    a[j] = f2bf(t[qq * 16 + j][cc]);
    b[j] = f2bf(t[qq * 16 + 8 + j][cc]);
  }
  *(u16x8*)o = a;
  *(u16x8*)(o + 8) = b;
}

__global__ void pack_bias(const float* __restrict__ bq, const float* __restrict__ bk,
                          const float* __restrict__ bv, float* __restrict__ o) {
  int i = blockIdx.x * 256 + threadIdx.x;  // 0..3071
  o[i] = i < 1024 ? bq[i] : (i < 2048 ? bk[i - 1024] : bv[i - 2048]);
}

// ---------- transpose V [bh][2048][64] -> Vt [bh][64][2048] (bf16) ----------
// kv columns PERMUTED within each 16-group (swap bits 2<->3) so attn's PV
// A-fragment (slots psi(g,hi,j)) is one contiguous b128 read.
__global__ void vtrans(const unsigned short* __restrict__ v, unsigned short* __restrict__ vt) {
  __shared__ __align__(16) unsigned short t[64][72];
  const int tid = threadIdx.x;
  const int bh = blockIdx.y, s0 = blockIdx.x * 64;
  const int r = tid >> 2, q = (tid & 3) * 16;
  const unsigned short* g = v + ((size_t)bh * 2048 + s0 + r) * 64 + q;
  *(u16x8*)&t[r][q] = *(const u16x8*)g;
  *(u16x8*)&t[r][q + 8] = *(const u16x8*)(g + 8);
  __syncthreads();
  const int d = tid >> 2, qq = (tid & 3) * 16;
  unsigned short* o = vt + ((size_t)bh * 64 + d) * 2048 + s0 + qq;
  u16x8 a, b;
#pragma unroll
  for (int j = 0; j < 8; ++j) {
    const int sa = (j & 3) | ((j & 4) << 1);   // 0,1,2,3,8,9,10,11
    a[j] = t[qq + sa][d];
    b[j] = t[qq + sa + 4][d];                  // 4,5,6,7,12,13,14,15
  }
  *(u16x8*)o = a;
  *(u16x8*)(o + 8) = b;
}

// ---------- bf16 GEMM 128x128: out[M][N] = A[M][K]*Bt[N][K]^T + bias ----------
// MODE 0: bf16 out, 1: +relu, 2: split q/k/v (+q pre-scale 0.125*log2e)
template <int MODE>
__global__ __launch_bounds__(256, 2) void gemm_bt(
    const unsigned short* __restrict__ A, const unsigned short* __restrict__ Bt,
    const float* __restrict__ bias, unsigned short* __restrict__ out,
    unsigned short* __restrict__ qb, unsigned short* __restrict__ kb,
    unsigned short* __restrict__ vb, int M, int N, int K) {
  __shared__ __align__(16) char As[16384];
  __shared__ __align__(16) char Bs[16384];
  const int tid = threadIdx.x;
  const int wave = tid >> 6, lane = tid & 63;
  const int lrow = lane & 15;
  const int kof = (lane >> 4) * 16;
  const int m0 = blockIdx.y * 128, n0 = blockIdx.x * 128;
  const int wm = (wave >> 1) * 64, wn = (wave & 1) * 64;
  const int chunkrow = lane >> 3;
  const int colb0 = (lane & 7) * 16;

  f32x4 acc[4][4] = {};

  for (int k0 = 0; k0 < K; k0 += 64) {
#pragma unroll
    for (int c = 0; c < 4; ++c) {
      const int chunk = wave * 4 + c;
      const int rowA = chunk * 8 + chunkrow;
      const int srcb = colb0 ^ ((rowA & 7) << 4);
      const char* ga = (const char*)A + ((size_t)(m0 + rowA) * K + k0) * 2 + srcb;
      const char* gb = (const char*)Bt + ((size_t)(n0 + rowA) * K + k0) * 2 + srcb;
      gload_lds16(ga, As + chunk * 1024);
      gload_lds16(gb, Bs + chunk * 1024);
    }
    __syncthreads();
#pragma unroll
    for (int kk = 0; kk < 2; ++kk) {
      bf16x8 af[4], bv4[4];
#pragma unroll
      for (int i = 0; i < 4; ++i) {
        const int ra = wm + i * 16 + lrow;
        af[i] = *(const bf16x8*)(As + ra * 128 + ((kk * 64 + kof) ^ ((ra & 7) << 4)));
        const int rb = wn + i * 16 + lrow;
        bv4[i] = *(const bf16x8*)(Bs + rb * 128 + ((kk * 64 + kof) ^ ((rb & 7) << 4)));
      }
#pragma unroll
      for (int mi = 0; mi < 4; ++mi)
#pragma unroll
        for (int ni = 0; ni < 4; ++ni)
          acc[mi][ni] = __builtin_amdgcn_mfma_f32_16x16x32_bf16(af[mi], bv4[ni], acc[mi][ni], 0, 0, 0);
    }
    __syncthreads();
  }

#pragma unroll
  for (int mi = 0; mi < 4; ++mi) {
    const int row = m0 + wm + mi * 16 + ((lane >> 4) << 2);
#pragma unroll
    for (int ni = 0; ni < 4; ++ni) {
      const int col = n0 + wn + ni * 16 + lrow;
      const float bvv = bias[col];
#pragma unroll
      for (int r = 0; r < 4; ++r) {
        float v = acc[mi][ni][r] + bvv;
        if (MODE == 1) v = fmaxf(v, 0.0f);
        const int rr = row + r;
        if constexpr (MODE == 2) {
          const int part = col >> 10, cc = col & 1023, h = cc >> 6, e = cc & 63;
          if (part == 0) v *= 0.18033688011112042f;  // 0.125*log2(e)
          unsigned short* dst = part == 0 ? qb : (part == 1 ? kb : vb);
          dst[(((size_t)((rr >> 11) * 16 + h)) * 2048 + (rr & 2047)) * 64 + e] = f2bf(v);
        } else {
          out[(size_t)rr * N + col] = f2bf(v);
        }
      }
    }
  }
}

// ---------- flash attention v5: 2 waves x 64 q-rows, staging amortized 2x ----------
// Per block: 128 q rows of one (b,h); each wave owns 64 q (2 groups of 32).
// K/V LDS tiles and kf/vf ds_reads are shared by both q-groups -> MFMA per
// staged byte doubles vs v4. Same swapped-MFMA/in-register-P structure.
__global__ __launch_bounds__(128, 2) void attn_kernel(
    const unsigned short* __restrict__ q_buf, const unsigned short* __restrict__ k_buf,
    const unsigned short* __restrict__ vt_buf, unsigned short* __restrict__ ctx) {
  __shared__ __align__(16) char Ks[2][8192];   // [64 kv][64 d] bf16, swizzled
  __shared__ __align__(16) char Vs[2][8192];   // [64 d][64 kv(perm)] bf16, swizzled
  const int tid = threadIdx.x, wave = tid >> 6, lane = tid & 63;
  const int wg = (blockIdx.x & 7) * 128 + (blockIdx.x >> 3);
  const int bh = wg >> 4;
  const int q0 = (wg & 15) * 128;
  const int l31 = lane & 31, hi = lane >> 5;

  // Q fragments (B-operand), 2 q-groups of 32 rows; q_buf pre-scaled
  bf16x8 qf[2][4];
#pragma unroll
  for (int qg = 0; qg < 2; ++qg)
#pragma unroll
    for (int kk = 0; kk < 4; ++kk)
      qf[qg][kk] = *(const bf16x8*)(q_buf +
          ((size_t)bh * 2048 + q0 + wave * 64 + qg * 32 + l31) * 64 + kk * 16 + hi * 8);

  f32x16 acc_o[2][2] = {};   // [qg][mtd]
  f32x16 accd[2] = {};       // [qg]
  bf16x8 ones;
#pragma unroll
  for (int j = 0; j < 8; ++j) ones[j] = (__bf16)1.0f;

  // stage K tile [64][64] + Vt tile [64][64] (4 gload16/wave each)
  auto stage = [&](int t, int buf) {
#pragma unroll
    for (int i = 0; i < 4; ++i) {
      const int c = i * 128 + wave * 64 + lane;           // 16B chunk index 0..511
      const int row = c >> 3;
      const int col = ((c & 7) * 16) ^ ((row & 7) << 4);  // pre-swizzled source col
      gload_lds16((const char*)k_buf + ((size_t)(bh * 2048 + t * 64 + row)) * 128 + col,
                  &Ks[buf][(i * 128 + wave * 64) * 16]);
      gload_lds16((const char*)vt_buf + ((size_t)(bh * 64 + row)) * 4096 + t * 128 + col,
                  &Vs[buf][(i * 128 + wave * 64) * 16]);
    }
  };

  stage(0, 0);
  for (int t = 0; t < 32; ++t) {
    const int cur = t & 1;
    __syncthreads();
    stage(t < 31 ? t + 1 : 31, cur ^ 1);

    // S^T = K * Q^T (M=64 kv via 2 m-tiles, N=32 q per group, K=64 d)
    f32x16 sacc[2][2] = {};   // [qg][mt]
#pragma unroll
    for (int kk = 0; kk < 4; ++kk) {
      bf16x8 kf[2];
#pragma unroll
      for (int mt = 0; mt < 2; ++mt) {
        const int row = mt * 32 + l31;
        kf[mt] = *(const bf16x8*)&Ks[cur][row * 128 + ((kk * 32 + hi * 16) ^ ((row & 7) << 4))];
      }
      __builtin_amdgcn_s_setprio(1);
#pragma unroll
      for (int qg = 0; qg < 2; ++qg)
#pragma unroll
        for (int mt = 0; mt < 2; ++mt)
          sacc[qg][mt] = __builtin_amdgcn_mfma_f32_32x32x16_bf16(kf[mt], qf[qg][kk], sacc[qg][mt], 0, 0, 0);
      __builtin_amdgcn_s_setprio(0);
    }

    // p = 2^s in place (scale folded into Q)
#pragma unroll
    for (int qg = 0; qg < 2; ++qg)
#pragma unroll
      for (int mt = 0; mt < 2; ++mt)
#pragma unroll
        for (int r = 0; r < 16; ++r)
          sacc[qg][mt][r] = fexp2(sacc[qg][mt][r]);

    // O^T += V^T * P^T ; den += ones * P^T. Sub-MFMA g covers
    // kv = 32(g>>1)+16(g&1)+8(j>>2)+4hi+(j&3); Vt pre-permuted so vf = one b128.
#pragma unroll
    for (int g = 0; g < 4; ++g) {
      const int m = g >> 1, c = g & 1;
      bf16x8 vf[2];
#pragma unroll
      for (int mtd = 0; mtd < 2; ++mtd) {
        const int row = mtd * 32 + l31;
        const int sw = (row & 7) << 4;
        vf[mtd] = *(const bf16x8*)&Vs[cur][row * 128 + ((g * 32 + hi * 16) ^ sw)];
      }
#pragma unroll
      for (int qg = 0; qg < 2; ++qg) {
        unsigned w0 = pkbf(sacc[qg][m][8 * c + 0], sacc[qg][m][8 * c + 1]);
        unsigned w1 = pkbf(sacc[qg][m][8 * c + 2], sacc[qg][m][8 * c + 3]);
        unsigned w2 = pkbf(sacc[qg][m][8 * c + 4], sacc[qg][m][8 * c + 5]);
        unsigned w3 = pkbf(sacc[qg][m][8 * c + 6], sacc[qg][m][8 * c + 7]);
        u32x4 bw = {w0, w1, w2, w3};
        bf16x8 pb = __builtin_bit_cast(bf16x8, bw);
        __builtin_amdgcn_s_setprio(1);
        accd[qg] = __builtin_amdgcn_mfma_f32_32x32x16_bf16(ones, pb, accd[qg], 0, 0, 0);
#pragma unroll
        for (int mtd = 0; mtd < 2; ++mtd)
          acc_o[qg][mtd] = __builtin_amdgcn_mfma_f32_32x32x16_bf16(vf[mtd], pb, acc_o[qg][mtd], 0, 0, 0);
        __builtin_amdgcn_s_setprio(0);
      }
    }
  }

  const int b = bh >> 4, h = bh & 15;
#pragma unroll
  for (int qg = 0; qg < 2; ++qg) {
    const float inv = 1.0f / accd[qg][0];
    const size_t orow = ((size_t)(b * 2048 + q0 + wave * 64 + qg * 32 + l31)) * 1024 + h * 64;
#pragma unroll
    for (int mtd = 0; mtd < 2; ++mtd)
#pragma unroll
      for (int gq = 0; gq < 4; ++gq) {
        u16x4 o;
#pragma unroll
        for (int e = 0; e < 4; ++e) o[e] = f2bf(acc_o[qg][mtd][gq * 4 + e] * inv);
        *(u16x4*)(ctx + orow + mtd * 32 + gq * 8 + hi * 4) = o;
      }
  }
}

// ---------- residual + layernorm (block per row, D=1024) ----------
template <bool RES_BF, bool OUT_F32>
__global__ __launch_bounds__(256) void ln_kernel(
    const unsigned short* __restrict__ xin, const void* __restrict__ res,
    const float* __restrict__ g, const float* __restrict__ b, void* __restrict__ out) {
  const int row = blockIdx.x, tid = threadIdx.x;
  const size_t base = (size_t)row * 1024 + tid * 4;
  float x[4];
  u16x4 xv = *(const u16x4*)(xin + base);
  if constexpr (RES_BF) {
    u16x4 rv = *(const u16x4*)((const unsigned short*)res + base);
#pragma unroll
    for (int j = 0; j < 4; ++j) x[j] = bf2f(xv[j]) + bf2f(rv[j]);
  } else {
    f32x4 rv = *(const f32x4*)((const float*)res + base);
#pragma unroll
    for (int j = 0; j < 4; ++j) x[j] = bf2f(xv[j]) + rv[j];
  }
  float s1 = 0.f, s2 = 0.f;
#pragma unroll
  for (int j = 0; j < 4; ++j) { s1 += x[j]; s2 += x[j] * x[j]; }
#pragma unroll
  for (int off = 32; off > 0; off >>= 1) {
    s1 += __shfl_down(s1, off);
    s2 += __shfl_down(s2, off);
  }
  __shared__ float red[8];
  const int wv = tid >> 6, ln = tid & 63;
  if (ln == 0) { red[wv] = s1; red[4 + wv] = s2; }
  __syncthreads();
  s1 = red[0] + red[1] + red[2] + red[3];
  s2 = red[4] + red[5] + red[6] + red[7];
  const float mu = s1 * (1.0f / 1024.0f);
  const float rs = rsqrtf(s2 * (1.0f / 1024.0f) - mu * mu + 1e-5f);
#pragma unroll
  for (int j = 0; j < 4; ++j) {
    const float y = (x[j] - mu) * rs * g[tid * 4 + j] + b[tid * 4 + j];
    if constexpr (OUT_F32) ((float*)out)[base + j] = y;
    else ((unsigned short*)out)[base + j] = f2bf(y);
  }
}

// ---------- workspace layout (bytes) ----------
static const size_t OFF_SBF  = 0;            // 16 MiB (bf16 src) ; reused as h1 later
static const size_t OFF_Q    = 16777216;
static const size_t OFF_K    = 33554432;
static const size_t OFF_V    = 50331648;
static const size_t OFF_VT   = 67108864;
static const size_t OFF_WQKV = 83886080;
static const size_t OFF_BQKV = 90177536;
static const size_t OFF_WO   = 90189824;
static const size_t OFF_W1   = 92286976;
static const size_t OFF_W2   = 100675584;
static const size_t OFF_CTX  = 109064192;
static const size_t OFF_AO   = 125841408;
static const size_t OFF_X1   = 142618624;
static const size_t OFF_FFN  = 159395840;
// total = 176173056 bytes

extern "C" void kernel_launch(void* const* d_in, const int* in_sizes, int n_in,
                              void* d_out, int out_size, void* d_ws, size_t ws_size,
                              hipStream_t stream) {
  const float* src = (const float*)d_in[0];
  const float* Wq  = (const float*)d_in[1];
  const float* bq  = (const float*)d_in[2];
  const float* Wk  = (const float*)d_in[3];
  const float* bk  = (const float*)d_in[4];
  const float* Wv  = (const float*)d_in[5];
  const float* bv  = (const float*)d_in[6];
  const float* Wo  = (const float*)d_in[7];
  const float* bo  = (const float*)d_in[8];
  const float* g1  = (const float*)d_in[9];
  const float* be1 = (const float*)d_in[10];
  const float* W1  = (const float*)d_in[11];
  const float* b1  = (const float*)d_in[12];
  const float* W2  = (const float*)d_in[13];
  const float* b2  = (const float*)d_in[14];
  const float* g2  = (const float*)d_in[15];
  const float* be2 = (const float*)d_in[16];

  char* ws = (char*)d_ws;
  unsigned short* sbf  = (unsigned short*)(ws + OFF_SBF);
  unsigned short* h1   = (unsigned short*)(ws + OFF_SBF);  // alias (sbf/q/k/v dead by then)
  unsigned short* qb   = (unsigned short*)(ws + OFF_Q);
  unsigned short* kb   = (unsigned short*)(ws + OFF_K);
  unsigned short* vb   = (unsigned short*)(ws + OFF_V);
  unsigned short* vtb  = (unsigned short*)(ws + OFF_VT);
  unsigned short* wqkv = (unsigned short*)(ws + OFF_WQKV);
  float*          bqkv = (float*)(ws + OFF_BQKV);
  unsigned short* wot  = (unsigned short*)(ws + OFF_WO);
  unsigned short* w1t  = (unsigned short*)(ws + OFF_W1);
  unsigned short* w2t  = (unsigned short*)(ws + OFF_W2);
  unsigned short* ctx  = (unsigned short*)(ws + OFF_CTX);
  unsigned short* ao   = (unsigned short*)(ws + OFF_AO);
  unsigned short* x1   = (unsigned short*)(ws + OFF_X1);
  unsigned short* ffn  = (unsigned short*)(ws + OFF_FFN);
  float* outp = (float*)d_out;

  // 1) casts / packing
  cvt_f32_bf16<<<dim3(8192), dim3(256), 0, stream>>>(src, sbf, 8388608);
  pack_qkv_w<<<dim3(16, 1, 48), dim3(256), 0, stream>>>(Wq, Wk, Wv, wqkv);
  pack_bias<<<dim3(12), dim3(256), 0, stream>>>(bq, bk, bv, bqkv);
  transpose_cvt<<<dim3(16, 16), dim3(256), 0, stream>>>(Wo, wot, 1024, 1024);
  transpose_cvt<<<dim3(16, 64), dim3(256), 0, stream>>>(W1, w1t, 1024, 4096);
  transpose_cvt<<<dim3(64, 16), dim3(256), 0, stream>>>(W2, w2t, 4096, 1024);

  // 2) QKV projection (128^2): [8192,1024] x [3072,1024]^T
  gemm_bt<2><<<dim3(24, 64), dim3(256), 0, stream>>>(sbf, wqkv, bqkv, nullptr, qb, kb, vb,
                                                     8192, 3072, 1024);
  // 3) V transpose (kv-permuted) for PV
  vtrans<<<dim3(32, 64), dim3(256), 0, stream>>>(vb, vtb);
  // 4) attention (2-wave blocks, 64 q/wave)
  attn_kernel<<<dim3(1024), dim3(128), 0, stream>>>(qb, kb, vtb, ctx);
  // 5) output projection (128^2)
  gemm_bt<0><<<dim3(8, 64), dim3(256), 0, stream>>>(ctx, wot, bo, ao, nullptr, nullptr, nullptr,
                                                    8192, 1024, 1024);
  // 6) LN1 (attn_out + src)
  ln_kernel<false, false><<<dim3(8192), dim3(256), 0, stream>>>(ao, src, g1, be1, x1);
  // 7) FFN (both on 128^2 — gemm8 retired after 3-round stop-loss)
  gemm_bt<1><<<dim3(32, 64), dim3(256), 0, stream>>>(x1, w1t, b1, h1, nullptr, nullptr, nullptr,
                                                     8192, 4096, 1024);
  gemm_bt<0><<<dim3(8, 64), dim3(256), 0, stream>>>(h1, w2t, b2, ffn, nullptr, nullptr, nullptr,
                                                    8192, 1024, 4096);
  // 8) LN2 (ffn + x1) -> f32 output
  ln_kernel<true, true><<<dim3(8192), dim3(256), 0, stream>>>(ffn, x1, g2, be2, outp);

  (void)in_sizes; (void)n_in; (void)out_size; (void)ws_size;
}